// Round 6
// baseline (1358.610 us; speedup 1.0000x reference)
//
#include <hip/hip_runtime.h>

// MS-SSIM loss, 5 levels.
// R16: barrier-free register-streaming rewrite. Post-mortem R10-R15:
//   five structurally different LDS+barrier kernels ALL pin at ~5-7
//   resident waves/CU (occ 13-21%) and ~125-157us; fill rises with
//   block count; VALUBusy 23-30%. Common factor: 2x syncthreads per
//   subtile (vmcnt(0) drains), 2-wave lockstep. R16 removes the
//   category: NO LDS, NO barriers. Wave = 64 cols x 64 rows; lane =
//   1 col; per row-step: 3 unaligned dwordx4 x2 imgs (lane-overlap
//   dedups in L1), H-conv for own col -> 11-deep REGISTER ring of
//   v4f H-results (chunk-of-11 unroll => all indices static, rule
//   #20), V-conv 11 static-slot pk-FMAs, SSIM epilogue, 1 atomic
//   per wave/band. Pool tree fused in L0 wave (row-pair regs +
//   shfl_down 2/4/8), levels 1-4 = same streaming kernel on padded
//   pyramid. launch_bounds(256,4) pins VGPR<=128 (4 waves/SIMD);
//   L0 grid 768 blocks = 3 blocks/CU fully resident.
//   VALU floor ~29us all levels; WRITE~38MB is the spill tripwire.
// Carried: channel-packed (x,y,xx+yy,xy) v4f conv; padded pyramid;
// spread atomics 1 line/slot; zero-pad row handling; tiny memset.

#define NIMG 48
#define NSLOT 256
#define SSTRIDE 16             // 64 B between slots -> 1 cache line each

// padded pyramid geometry (8 zero cols each side)
#define RS1 272
#define RS2 144
#define RS3 80
#define RS4 48
#define IS0 (512L*512)
#define IS1 (256L*272)
#define IS2 (128L*144)
#define IS3 (64L*80)
#define IS4 (32L*48)

typedef float v4f __attribute__((ext_vector_type(4)));
typedef float uf4 __attribute__((ext_vector_type(4), aligned(4)));

struct Pyr {
    float *x1, *y1, *x2, *y2, *x3, *y3, *x4, *y4;
};

#define GDEF const float G[11] = { \
    0.00102839f, 0.00759877f, 0.03600077f, 0.10936069f, 0.21300539f, \
    0.26601173f, 0.21300539f, 0.10936069f, 0.03600077f, 0.00759877f, \
    0.00102839f };

__device__ __forceinline__ void load12(const float* rp, int cb, float* w)
{
#pragma unroll
    for (int v = 0; v < 3; ++v) {
        const uf4 a = *reinterpret_cast<const uf4*>(rp + cb + 4 * v);
        w[4*v+0] = a.x; w[4*v+1] = a.y; w[4*v+2] = a.z; w[4*v+3] = a.w;
    }
}

__device__ __forceinline__ void load12g(const float* rp, int cb, int W, float* w)
{
#pragma unroll
    for (int e = 0; e < 12; ++e) {
        const int col = cb + e;
        w[e] = ((unsigned)col < (unsigned)W) ? rp[col] : 0.0f;
    }
}

// H-conv at this lane's col from its 12-col window: v4f (x, y, xx+yy, xy)
__device__ __forceinline__ v4f h_of_row(const float* xw, const float* yw)
{
    GDEF
    v4f s = {0.f, 0.f, 0.f, 0.f};
#pragma unroll
    for (int k = 0; k < 11; ++k) {
        const float a = xw[k], b = yw[k];
        v4f w; w.x = a; w.y = b; w.z = a*a + b*b; w.w = a*b;
        s += w * G[k];                     // 2x v_pk_fma_f32
    }
    return s;
}

__device__ __forceinline__ float ssim_px(const v4f acc)
{
    const float C1 = 4.0e-4f;
    const float C2 = 3.6e-3f;
    const float mu1 = acc.x, mu2 = acc.y;
    const float mu1s = mu1*mu1, mu2s = mu2*mu2, m12 = mu1*mu2;
    const float ssum = acc.z - mu1s - mu2s;        // sig1+sig2
    const float s12  = acc.w - m12;
    const float num = (2.f * m12 + C1) * (2.f * s12 + C2);
    const float den = (mu1s + mu2s + C1) * (ssum + C2);
    return num * __builtin_amdgcn_rcpf(den + 1e-8f);
}

// ---- L0: streaming SSIM + fused pyramid build. 768 blocks x 256 thr ----
// wave (wid): band = wid&7 (64 rows), strip = (wid>>3)&7 (64 cols), z = wid>>6.
__global__ __launch_bounds__(256, 4) void ssim_l0_stream(
    const float* __restrict__ x, const float* __restrict__ y,
    Pyr p, float* __restrict__ slots)
{
    GDEF
    const int t    = threadIdx.x;
    const int lane = t & 63;
    const int wid  = blockIdx.x * 4 + (t >> 6);
    const int R0   = (wid & 7) * 64;
    const int strip = (wid >> 3) & 7;
    const int C0   = strip * 64;
    const int z    = wid >> 6;
    const float* xi = x + (long)z * IS0;
    const float* yi = y + (long)z * IS0;
    const int cb   = C0 + lane - 5;       // window base col
    const int cg   = C0 + lane;           // own col
    const bool edge = (strip == 0) | (strip == 7);
    const bool padL = (strip == 0), padR = (strip == 7);

    float* q1x = p.x1 + (long)z * IS1;  float* q1y = p.y1 + (long)z * IS1;
    float* q2x = p.x2 + (long)z * IS2;  float* q2y = p.y2 + (long)z * IS2;
    float* q3x = p.x3 + (long)z * IS3;  float* q3y = p.y3 + (long)z * IS3;
    float* q4x = p.x4 + (long)z * IS4;  float* q4y = p.y4 + (long)z * IS4;

    v4f hb[11];
    float pxc = 0.f, pxc1 = 0.f, pyc = 0.f, pyc1 = 0.f;   // prev raw pair
    float v1px = 0.f, v1py = 0.f, v2px = 0.f, v2py = 0.f, v3px = 0.f, v3py = 0.f;
    float local = 0.f;

    // one streaming step: load row l = R0-5+s, pool, return H-row
    auto step = [&](int s) -> v4f {
        const int l = R0 - 5 + s;
        float xw[12], yw[12];
        const bool rowOK = ((unsigned)l < 512u);
        if (rowOK) {
            const float* xr = xi + (long)l * 512;
            const float* yr = yi + (long)l * 512;
            if (!edge) { load12(xr, cb, xw); load12(yr, cb, yw); }
            else       { load12g(xr, cb, 512, xw); load12g(yr, cb, 512, yw); }
        } else {
#pragma unroll
            for (int e = 0; e < 12; ++e) { xw[e] = 0.f; yw[e] = 0.f; }
        }
        // fused pool over rows [R0, R0+64) (l wave-uniform -> uniform branches)
        if ((unsigned)(l - R0) < 64u) {
            const float xc = xw[5], xc1 = xw[6], yc = yw[5], yc1 = yw[6];
            if (l & 1) {
                const float v1x = 0.25f * (pxc + pxc1 + xc + xc1);
                const float v1y = 0.25f * (pyc + pyc1 + yc + yc1);
                const int r1 = l >> 1;
                if (!(lane & 1)) {
                    q1x[(long)r1 * RS1 + (cg >> 1)] = v1x;
                    q1y[(long)r1 * RS1 + (cg >> 1)] = v1y;
                }
                if ((l & 3) == 1) { v1px = v1x; v1py = v1y; }
                else {
                    const float v2x = 0.25f * (v1px + v1x
                        + __shfl_down(v1px, 2, 64) + __shfl_down(v1x, 2, 64));
                    const float v2y = 0.25f * (v1py + v1y
                        + __shfl_down(v1py, 2, 64) + __shfl_down(v1y, 2, 64));
                    if (!(lane & 3)) {
                        q2x[(long)(l >> 2) * RS2 + (cg >> 2)] = v2x;
                        q2y[(long)(l >> 2) * RS2 + (cg >> 2)] = v2y;
                    }
                    if ((l & 7) == 3) { v2px = v2x; v2py = v2y; }
                    else {
                        const float v3x = 0.25f * (v2px + v2x
                            + __shfl_down(v2px, 4, 64) + __shfl_down(v2x, 4, 64));
                        const float v3y = 0.25f * (v2py + v2y
                            + __shfl_down(v2py, 4, 64) + __shfl_down(v2y, 4, 64));
                        if (!(lane & 7)) {
                            q3x[(long)(l >> 3) * RS3 + (cg >> 3)] = v3x;
                            q3y[(long)(l >> 3) * RS3 + (cg >> 3)] = v3y;
                        }
                        if ((l & 15) == 7) { v3px = v3x; v3py = v3y; }
                        else {
                            const float v4x = 0.25f * (v3px + v3x
                                + __shfl_down(v3px, 8, 64) + __shfl_down(v3x, 8, 64));
                            const float v4y = 0.25f * (v3py + v3y
                                + __shfl_down(v3py, 8, 64) + __shfl_down(v3y, 8, 64));
                            if (!(lane & 15)) {
                                q4x[(long)(l >> 4) * RS4 + (cg >> 4)] = v4x;
                                q4y[(long)(l >> 4) * RS4 + (cg >> 4)] = v4y;
                            }
                        }
                    }
                }
                // zero col-pads of all levels (edge strips only)
                if (padL && lane < 8) {
                    q1x[(long)r1 * RS1 - 8 + lane] = 0.f;
                    q1y[(long)r1 * RS1 - 8 + lane] = 0.f;
                    if ((l & 3) == 3) { q2x[(long)(l>>2)*RS2 - 8 + lane] = 0.f;
                                        q2y[(long)(l>>2)*RS2 - 8 + lane] = 0.f; }
                    if ((l & 7) == 7) { q3x[(long)(l>>3)*RS3 - 8 + lane] = 0.f;
                                        q3y[(long)(l>>3)*RS3 - 8 + lane] = 0.f; }
                    if ((l & 15) == 15) { q4x[(long)(l>>4)*RS4 - 8 + lane] = 0.f;
                                          q4y[(long)(l>>4)*RS4 - 8 + lane] = 0.f; }
                }
                if (padR && lane < 8) {
                    q1x[(long)r1 * RS1 + 256 + lane] = 0.f;
                    q1y[(long)r1 * RS1 + 256 + lane] = 0.f;
                    if ((l & 3) == 3) { q2x[(long)(l>>2)*RS2 + 128 + lane] = 0.f;
                                        q2y[(long)(l>>2)*RS2 + 128 + lane] = 0.f; }
                    if ((l & 7) == 7) { q3x[(long)(l>>3)*RS3 + 64 + lane] = 0.f;
                                        q3y[(long)(l>>3)*RS3 + 64 + lane] = 0.f; }
                    if ((l & 15) == 15) { q4x[(long)(l>>4)*RS4 + 32 + lane] = 0.f;
                                          q4y[(long)(l>>4)*RS4 + 32 + lane] = 0.f; }
                }
            }
            pxc = xw[5]; pxc1 = xw[6]; pyc = yw[5]; pyc1 = yw[6];
        }
        return h_of_row(xw, yw);
    };

    // warmup: slots 0..9 (rows R0-5 .. R0+4)
#pragma unroll
    for (int s = 0; s < 10; ++s) hb[s] = step(s);

    // main: 6 chunks x 11 steps (steps 10..75 -> 66 slots, 64 real outputs)
    for (int cc = 0; cc < 6; ++cc) {
        const int sb = 10 + cc * 11;
#pragma unroll
        for (int j = 0; j < 11; ++j) {
            const int s = sb + j;
            hb[(j + 10) % 11] = step(s);       // static slot
            v4f acc = {0.f, 0.f, 0.f, 0.f};
#pragma unroll
            for (int k = 0; k < 11; ++k)
                acc += hb[(j + k) % 11] * G[k]; // static slots
            if (s < 74) local += ssim_px(acc);
        }
    }

#pragma unroll
    for (int off = 32; off > 0; off >>= 1) local += __shfl_down(local, off, 64);
    if (lane == 0) atomicAdd(slots + (wid & (NSLOT - 1)) * SSTRIDE, local);
}

// ---- levels 1-4, streaming. 264 blocks x 256 thr = 1056 waves ----
// L1: 768 (4 strips x 4 bands x 48), L2: 192 (2x2x48), L3: 48, L4: 48.
__global__ __launch_bounds__(256, 4) void ssim_lvls_stream(
    Pyr p, float* __restrict__ slots)
{
    GDEF
    const int t    = threadIdx.x;
    const int lane = t & 63;
    const int wid  = blockIdx.x * 4 + (t >> 6);

    const float* xi; const float* yi;
    int rs, H, W, C0, R0, nch, lvl;
    if (wid < 768) {
        lvl = 1; const int r = wid & 15, z = wid >> 4;
        xi = p.x1 + (long)z * IS1; yi = p.y1 + (long)z * IS1;
        rs = RS1; H = W = 256; C0 = (r & 3) * 64; R0 = (r >> 2) * 64; nch = 6;
    } else if (wid < 960) {
        lvl = 2; const int w2 = wid - 768; const int r = w2 & 3, z = w2 >> 2;
        xi = p.x2 + (long)z * IS2; yi = p.y2 + (long)z * IS2;
        rs = RS2; H = W = 128; C0 = (r & 1) * 64; R0 = ((r >> 1) & 1) * 64; nch = 6;
    } else if (wid < 1008) {
        lvl = 3; const int z = wid - 960;
        xi = p.x3 + (long)z * IS3; yi = p.y3 + (long)z * IS3;
        rs = RS3; H = W = 64; C0 = 0; R0 = 0; nch = 6;
    } else {
        lvl = 4; const int z = wid - 1008;
        xi = p.x4 + (long)z * IS4; yi = p.y4 + (long)z * IS4;
        rs = RS4; H = W = 32; C0 = 0; R0 = 0; nch = 3;
    }
    const int cb = C0 + lane - 5;
    const int cg = C0 + lane;
    const int smax = 10 + ((H - R0 < 64) ? (H - R0) : 64);

    v4f hb[11];
    float local = 0.f;

    auto step = [&](int s) -> v4f {
        const int l = R0 - 5 + s;
        float xw[12], yw[12];
        if ((unsigned)l < (unsigned)H) {
            // pads guarantee cols [-8, W+8); beyond reads adjacent rows
            // (allocated, finite, discarded by col check)
            load12(xi + (long)l * rs, cb, xw);
            load12(yi + (long)l * rs, cb, yw);
        } else {
#pragma unroll
            for (int e = 0; e < 12; ++e) { xw[e] = 0.f; yw[e] = 0.f; }
        }
        return h_of_row(xw, yw);
    };

#pragma unroll
    for (int s = 0; s < 10; ++s) hb[s] = step(s);

    for (int cc = 0; cc < nch; ++cc) {
        const int sb = 10 + cc * 11;
#pragma unroll
        for (int j = 0; j < 11; ++j) {
            const int s = sb + j;
            hb[(j + 10) % 11] = step(s);
            v4f acc = {0.f, 0.f, 0.f, 0.f};
#pragma unroll
            for (int k = 0; k < 11; ++k)
                acc += hb[(j + k) % 11] * G[k];
            if (s < smax && cg < W) local += ssim_px(acc);
        }
    }

#pragma unroll
    for (int off = 32; off > 0; off >>= 1) local += __shfl_down(local, off, 64);
    if (lane == 0)
        atomicAdd(slots + ((long)lvl * NSLOT + (wid & (NSLOT - 1))) * SSTRIDE,
                  local);
}

__global__ void finalize_kernel(const float* __restrict__ slots,
                                float* __restrict__ out)
{
    const int t = threadIdx.x;
    const float w[5] = {0.0448f, 0.2856f, 0.3001f, 0.2363f, 0.1333f};
    const float wsum = w[0] + w[1] + w[2] + w[3] + w[4];
    float acc = 0.f;
#pragma unroll
    for (int lvl = 0; lvl < 5; ++lvl) {
        const int d = 512 >> lvl;
        const float cnt = (float)NIMG * (float)d * (float)d;
        acc += (w[lvl] / wsum) / cnt * slots[(lvl * NSLOT + t) * SSTRIDE];
    }
#pragma unroll
    for (int off = 32; off > 0; off >>= 1) acc += __shfl_down(acc, off, 64);
    __shared__ float pp[4];
    if ((t & 63) == 0) pp[t >> 6] = acc;
    __syncthreads();
    if (t == 0) out[0] = 1.0f - (pp[0] + pp[1] + pp[2] + pp[3]);
}

extern "C" void kernel_launch(void* const* d_in, const int* in_sizes, int n_in,
                              void* d_out, int out_size, void* d_ws, size_t ws_size,
                              hipStream_t stream)
{
    const float* pred = (const float*)d_in[0];
    const float* targ = (const float*)d_in[1];
    float* out = (float*)d_out;
    float* ws  = (float*)d_ws;

    float* slots = ws;                           // 5 * 256 * 16 floats (80 KB)
    float* zpad  = slots + 5 * NSLOT * SSTRIDE;  // 640 zero floats (unused now)

    Pyr p;
    {
        float* b = zpad + 640;
        p.x1 = b + 8;                 b += NIMG * IS1;
        p.y1 = b + 8;                 b += NIMG * IS1;
        p.x2 = b + 8;                 b += NIMG * IS2;
        p.y2 = b + 8;                 b += NIMG * IS2;
        p.x3 = b + 8;                 b += NIMG * IS3;
        p.y3 = b + 8;                 b += NIMG * IS3;
        p.x4 = b + 8;                 b += NIMG * IS4;
        p.y4 = b + 8;                 // + NIMG*IS4 + 1024 floats slack in ws
    }

    hipMemsetAsync(ws, 0, (size_t)(5 * NSLOT * SSTRIDE + 640) * sizeof(float),
                   stream);

    // L0 + fused pyramid: 3072 waves = 768 blocks (3 blocks/CU, all resident)
    ssim_l0_stream<<<dim3(768), 256, 0, stream>>>(pred, targ, p, slots);
    // L1-4: 1056 waves = 264 blocks
    ssim_lvls_stream<<<dim3(264), 256, 0, stream>>>(p, slots);

    finalize_kernel<<<1, 256, 0, stream>>>(slots, out);
}

// Round 7
// 819.344 us; speedup vs baseline: 1.6582x; 1.6582x over previous
//
#include <hip/hip_runtime.h>

// MS-SSIM loss, 5 levels.
// R17: register-streaming, codegen-disciplined. Post-mortem R16: right
//   structure (no LDS/barriers, absmax 0) but hb[11] ring + giant lambda
//   defeated SROA -> scratch (VGPR 64, WRITE 1.34GB, FETCH 950MB, 3.7GB
//   scratch @ 2.15TB/s = 1.09ms, closed form). R17 forces registers:
//   (a) ring = 11 NAMED v4f h0..h10, rotated by macro operand naming in
//       an 11-step chunk -- zero array indexing anywhere.
//   (b) no lambdas; tiny __forceinline__ row helpers with own locals.
//   (c) 64-thr blocks (1 wave): tile math + 8 pyramid ptrs from blockIdx
//       -> SGPRs (256-thr blocks made them per-thread = ~32 VGPRs).
//   (d) pool = compact phase at kernel head (R14-proven shfl tree,
//       aligned float4 loads, warms L2; regs dead before ring lives).
//   (e) zero stores in streaming body -> compiler hoists next-row loads
//       across current-row FMAs freely.
//   Live set ~85 VGPR; launch_bounds(64,4) caps 128. L0 3072 waves,
//   lvls 1056. WRITE ~36MB is the spill tripwire.
// Carried: channel-packed (x,y,xx+yy,xy) v4f conv; padded pyramid
// (+8 col pads, zeroed by edge-strip waves); spread atomics; lane=
// own-column H (zero H recompute, minimal-FLOP arrangement).

#define NIMG 48
#define NSLOT 256
#define SSTRIDE 16             // 64 B between slots -> 1 cache line each

// padded pyramid geometry (8 zero cols each side)
#define RS1 272
#define RS2 144
#define RS3 80
#define RS4 48
#define IS0 (512L*512)
#define IS1 (256L*272)
#define IS2 (128L*144)
#define IS3 (64L*80)
#define IS4 (32L*48)

typedef float v4f __attribute__((ext_vector_type(4)));
typedef float uf4 __attribute__((ext_vector_type(4), aligned(4)));

struct Pyr { float *x1, *y1, *x2, *y2, *x3, *y3, *x4, *y4; };

#define GDEF const float G[11] = { \
    0.00102839f, 0.00759877f, 0.03600077f, 0.10936069f, 0.21300539f, \
    0.26601173f, 0.21300539f, 0.10936069f, 0.03600077f, 0.00759877f, \
    0.00102839f };

__device__ __forceinline__ void load12(const float* rp, int cb, float* w)
{
#pragma unroll
    for (int v = 0; v < 3; ++v) {
        const uf4 a = *reinterpret_cast<const uf4*>(rp + cb + 4 * v);
        w[4*v+0] = a.x; w[4*v+1] = a.y; w[4*v+2] = a.z; w[4*v+3] = a.w;
    }
}

__device__ __forceinline__ void load12g(const float* rp, int cb, int W, float* w)
{
#pragma unroll
    for (int e = 0; e < 12; ++e) {
        const int col = cb + e;
        w[e] = ((unsigned)col < (unsigned)W) ? rp[col] : 0.0f;
    }
}

// H-conv at this lane's col: v4f (x, y, xx+yy, xy)
__device__ __forceinline__ v4f h_of_row(const float* xw, const float* yw)
{
    GDEF
    v4f s = {0.f, 0.f, 0.f, 0.f};
#pragma unroll
    for (int k = 0; k < 11; ++k) {
        const float a = xw[k], b = yw[k];
        v4f w; w.x = a; w.y = b; w.z = a*a + b*b; w.w = a*b;
        s += w * G[k];                     // 2x v_pk_fma_f32
    }
    return s;
}

__device__ __forceinline__ float ssim_px(const v4f acc)
{
    const float C1 = 4.0e-4f;
    const float C2 = 3.6e-3f;
    const float mu1 = acc.x, mu2 = acc.y;
    const float mu1s = mu1*mu1, mu2s = mu2*mu2, m12 = mu1*mu2;
    const float ssum = acc.z - mu1s - mu2s;        // sig1+sig2
    const float s12  = acc.w - m12;
    const float num = (2.f * m12 + C1) * (2.f * s12 + C2);
    const float den = (mu1s + mu2s + C1) * (ssum + C2);
    return num * __builtin_amdgcn_rcpf(den + 1e-8f);
}

__device__ __forceinline__ v4f l0_hrow(const float* xi, const float* yi,
                                       int l, int cb, bool edge)
{
    float xw[12], yw[12];
    if ((unsigned)l < 512u) {
        const float* xr = xi + (long)l * 512;
        const float* yr = yi + (long)l * 512;
        if (!edge) { load12(xr, cb, xw); load12(yr, cb, yw); }
        else       { load12g(xr, cb, 512, xw); load12g(yr, cb, 512, yw); }
    } else {
#pragma unroll
        for (int e = 0; e < 12; ++e) { xw[e] = 0.f; yw[e] = 0.f; }
    }
    return h_of_row(xw, yw);
}

__device__ __forceinline__ v4f lv_hrow(const float* xi, const float* yi,
                                       int l, int cb, int H, int rs, bool laneOK)
{
    float xw[12], yw[12];
    if (((unsigned)l < (unsigned)H) && laneOK) {
        load12(xi + (long)l * rs, cb, xw);       // pads cover [-8, W+8)
        load12(yi + (long)l * rs, cb, yw);
    } else {
#pragma unroll
        for (int e = 0; e < 12; ++e) { xw[e] = 0.f; yw[e] = 0.f; }
    }
    return h_of_row(xw, yw);
}

// ring step macros: dst gets row l (the r+5 row); acc spans s0..s9,dst
#define RSTEP0(dst, s0,s1,s2,s3,s4,s5,s6,s7,s8,s9)                      \
    { dst = l0_hrow(xi, yi, l, cb, edge);                               \
      v4f acc = s0 * G[0];                                              \
      acc += s1*G[1]; acc += s2*G[2]; acc += s3*G[3]; acc += s4*G[4];   \
      acc += s5*G[5]; acc += s6*G[6]; acc += s7*G[7]; acc += s8*G[8];   \
      acc += s9*G[9]; acc += dst*G[10];                                 \
      if (m < 64) local += ssim_px(acc);                                \
      ++l; ++m; }

#define RSTEPL(dst, s0,s1,s2,s3,s4,s5,s6,s7,s8,s9)                      \
    { dst = lv_hrow(xi, yi, l, cb, H, rs, laneOK);                      \
      v4f acc = s0 * G[0];                                              \
      acc += s1*G[1]; acc += s2*G[2]; acc += s3*G[3]; acc += s4*G[4];   \
      acc += s5*G[5]; acc += s6*G[6]; acc += s7*G[7]; acc += s8*G[8];   \
      acc += s9*G[9]; acc += dst*G[10];                                 \
      if (m < mmax && laneOK) local += ssim_px(acc);                    \
      ++l; ++m; }

#define CHUNK(RS)                                   \
    RS(h10, h0,h1,h2,h3,h4,h5,h6,h7,h8,h9)          \
    RS(h0,  h1,h2,h3,h4,h5,h6,h7,h8,h9,h10)         \
    RS(h1,  h2,h3,h4,h5,h6,h7,h8,h9,h10,h0)         \
    RS(h2,  h3,h4,h5,h6,h7,h8,h9,h10,h0,h1)         \
    RS(h3,  h4,h5,h6,h7,h8,h9,h10,h0,h1,h2)         \
    RS(h4,  h5,h6,h7,h8,h9,h10,h0,h1,h2,h3)         \
    RS(h5,  h6,h7,h8,h9,h10,h0,h1,h2,h3,h4)         \
    RS(h6,  h7,h8,h9,h10,h0,h1,h2,h3,h4,h5)         \
    RS(h7,  h8,h9,h10,h0,h1,h2,h3,h4,h5,h6)         \
    RS(h8,  h9,h10,h0,h1,h2,h3,h4,h5,h6,h7)         \
    RS(h9,  h10,h0,h1,h2,h3,h4,h5,h6,h7,h8)

// ---- L0: pool (head) + streaming SSIM. 3072 blocks x 64 thr ----
__global__ __launch_bounds__(64, 4) void ssim_l0_stream(
    const float* __restrict__ x, const float* __restrict__ y,
    Pyr p, float* __restrict__ slots)
{
    GDEF
    const int lane  = threadIdx.x;
    const int wid   = blockIdx.x;
    const int R0    = (wid & 7) * 64;
    const int strip = (wid >> 3) & 7;
    const int C0    = strip * 64;
    const int z     = wid >> 6;
    const float* xi = x + (long)z * IS0;
    const float* yi = y + (long)z * IS0;
    const bool edge = (strip == 0) | (strip == 7);

    float* q1x = p.x1 + (long)z * IS1;  float* q1y = p.y1 + (long)z * IS1;
    float* q2x = p.x2 + (long)z * IS2;  float* q2y = p.y2 + (long)z * IS2;
    float* q3x = p.x3 + (long)z * IS3;  float* q3y = p.y3 + (long)z * IS3;
    float* q4x = p.x4 + (long)z * IS4;  float* q4y = p.y4 + (long)z * IS4;

    // ---- pool phase: lane owns an 8x8 patch of this 64x64 tile ----
    {
        const int r8 = lane >> 3, c8 = lane & 7;
        const int pr0 = R0 + 8 * r8, pc0 = C0 + 8 * c8;
        float x3x = 0.f, x3y = 0.f;
#pragma unroll
        for (int q2 = 0; q2 < 2; ++q2) {
            float sx0 = 0.f, sx1 = 0.f, sy0 = 0.f, sy1 = 0.f;
#pragma unroll
            for (int q1 = 0; q1 < 2; ++q1) {
                const int ir = pr0 + 4*q2 + 2*q1;
                const float* xr = xi + (long)ir * 512 + pc0;
                const float* yr = yi + (long)ir * 512 + pc0;
                const float4 a0 = *reinterpret_cast<const float4*>(xr);
                const float4 a1 = *reinterpret_cast<const float4*>(xr + 4);
                const float4 a2 = *reinterpret_cast<const float4*>(xr + 512);
                const float4 a3 = *reinterpret_cast<const float4*>(xr + 516);
                const float4 b0 = *reinterpret_cast<const float4*>(yr);
                const float4 b1 = *reinterpret_cast<const float4*>(yr + 4);
                const float4 b2 = *reinterpret_cast<const float4*>(yr + 512);
                const float4 b3 = *reinterpret_cast<const float4*>(yr + 516);
                const float qx0 = 0.25f*(a0.x+a0.y+a2.x+a2.y);
                const float qx1 = 0.25f*(a0.z+a0.w+a2.z+a2.w);
                const float qx2 = 0.25f*(a1.x+a1.y+a3.x+a3.y);
                const float qx3 = 0.25f*(a1.z+a1.w+a3.z+a3.w);
                const float qy0 = 0.25f*(b0.x+b0.y+b2.x+b2.y);
                const float qy1 = 0.25f*(b0.z+b0.w+b2.z+b2.w);
                const float qy2 = 0.25f*(b1.x+b1.y+b3.x+b3.y);
                const float qy3 = 0.25f*(b1.z+b1.w+b3.z+b3.w);
                float4 ox; ox.x=qx0; ox.y=qx1; ox.z=qx2; ox.w=qx3;
                float4 oy; oy.x=qy0; oy.y=qy1; oy.z=qy2; oy.w=qy3;
                *reinterpret_cast<float4*>(q1x + (long)(ir>>1)*RS1 + (pc0>>1)) = ox;
                *reinterpret_cast<float4*>(q1y + (long)(ir>>1)*RS1 + (pc0>>1)) = oy;
                sx0 += qx0+qx1; sx1 += qx2+qx3;
                sy0 += qy0+qy1; sy1 += qy2+qy3;
            }
            const float v2x0 = 0.25f*sx0, v2x1 = 0.25f*sx1;
            const float v2y0 = 0.25f*sy0, v2y1 = 0.25f*sy1;
            *reinterpret_cast<float2*>(q2x + (long)((pr0>>2)+q2)*RS2 + (pc0>>2))
                = make_float2(v2x0, v2x1);
            *reinterpret_cast<float2*>(q2y + (long)((pr0>>2)+q2)*RS2 + (pc0>>2))
                = make_float2(v2y0, v2y1);
            x3x += v2x0+v2x1; x3y += v2y0+v2y1;
        }
        x3x *= 0.25f; x3y *= 0.25f;
        q3x[(long)(pr0>>3)*RS3 + (pc0>>3)] = x3x;
        q3y[(long)(pr0>>3)*RS3 + (pc0>>3)] = x3y;
        const float v4x = 0.25f*(x3x + __shfl_down(x3x,1,64)
                               + __shfl_down(x3x,8,64) + __shfl_down(x3x,9,64));
        const float v4y = 0.25f*(x3y + __shfl_down(x3y,1,64)
                               + __shfl_down(x3y,8,64) + __shfl_down(x3y,9,64));
        if (!(r8 & 1) && !(c8 & 1)) {
            q4x[(long)(pr0>>4)*RS4 + (pc0>>4)] = v4x;
            q4y[(long)(pr0>>4)*RS4 + (pc0>>4)] = v4y;
        }
        // zero the 8-col pads of all levels (edge strips only)
        if (edge) {
            const bool left = (strip == 0);
            const int p1c = left ? (c8 - 8) : (256 + c8);
            const int p2c = left ? (c8 - 8) : (128 + c8);
            const int p3c = left ? (c8 - 8) : (64 + c8);
            const int p4c = left ? (c8 - 8) : (32 + c8);
#pragma unroll
            for (int i = 0; i < 4; ++i) {
                const int rr = (R0>>1) + 8*i + r8;
                q1x[(long)rr*RS1 + p1c] = 0.f; q1y[(long)rr*RS1 + p1c] = 0.f;
            }
#pragma unroll
            for (int i = 0; i < 2; ++i) {
                const int rr = (R0>>2) + 8*i + r8;
                q2x[(long)rr*RS2 + p2c] = 0.f; q2y[(long)rr*RS2 + p2c] = 0.f;
            }
            { const int rr = (R0>>3) + r8;
              q3x[(long)rr*RS3 + p3c] = 0.f; q3y[(long)rr*RS3 + p3c] = 0.f; }
            if (r8 < 4) {
                const int rr = (R0>>4) + r8;
                q4x[(long)rr*RS4 + p4c] = 0.f; q4y[(long)rr*RS4 + p4c] = 0.f;
            }
        }
    }

    // ---- streaming SSIM: 11-deep named-register ring ----
    const int cb = C0 + lane - 5;
    v4f h0,h1,h2,h3,h4,h5,h6,h7,h8,h9,h10;
    {
        int l = R0 - 5;
        h0 = l0_hrow(xi, yi, l++, cb, edge);
        h1 = l0_hrow(xi, yi, l++, cb, edge);
        h2 = l0_hrow(xi, yi, l++, cb, edge);
        h3 = l0_hrow(xi, yi, l++, cb, edge);
        h4 = l0_hrow(xi, yi, l++, cb, edge);
        h5 = l0_hrow(xi, yi, l++, cb, edge);
        h6 = l0_hrow(xi, yi, l++, cb, edge);
        h7 = l0_hrow(xi, yi, l++, cb, edge);
        h8 = l0_hrow(xi, yi, l++, cb, edge);
        h9 = l0_hrow(xi, yi, l++, cb, edge);
    }
    float local = 0.f;
    {
        int l = R0 + 5, m = 0;
        for (int cc = 0; cc < 6; ++cc) {
            CHUNK(RSTEP0)
        }
    }

#pragma unroll
    for (int off = 32; off > 0; off >>= 1) local += __shfl_down(local, off, 64);
    if (lane == 0) atomicAdd(slots + (wid & (NSLOT - 1)) * SSTRIDE, local);
}

// ---- levels 1-4, streaming. 1056 blocks x 64 thr ----
__global__ __launch_bounds__(64, 4) void ssim_lvls_stream(
    Pyr p, float* __restrict__ slots)
{
    GDEF
    const int lane = threadIdx.x;
    const int wid  = blockIdx.x;

    const float* xi; const float* yi;
    int rs, H, W, C0, R0, lvl;
    if (wid < 768) {
        lvl = 1; const int r = wid & 15, z = wid >> 4;
        xi = p.x1 + (long)z * IS1; yi = p.y1 + (long)z * IS1;
        rs = RS1; H = W = 256; C0 = (r & 3) * 64; R0 = (r >> 2) * 64;
    } else if (wid < 960) {
        lvl = 2; const int w2 = wid - 768; const int r = w2 & 3, z = w2 >> 2;
        xi = p.x2 + (long)z * IS2; yi = p.y2 + (long)z * IS2;
        rs = RS2; H = W = 128; C0 = (r & 1) * 64; R0 = ((r >> 1) & 1) * 64;
    } else if (wid < 1008) {
        lvl = 3; const int z = wid - 960;
        xi = p.x3 + (long)z * IS3; yi = p.y3 + (long)z * IS3;
        rs = RS3; H = W = 64; C0 = 0; R0 = 0;
    } else {
        lvl = 4; const int z = wid - 1008;
        xi = p.x4 + (long)z * IS4; yi = p.y4 + (long)z * IS4;
        rs = RS4; H = W = 32; C0 = 0; R0 = 0;
    }
    const int cb = C0 + lane - 5;
    const bool laneOK = (C0 + lane) < W;
    const int mmax = (H - R0 < 64) ? (H - R0) : 64;
    const int nch  = (mmax + 10) / 11;

    v4f h0,h1,h2,h3,h4,h5,h6,h7,h8,h9,h10;
    {
        int l = R0 - 5;
        h0 = lv_hrow(xi, yi, l++, cb, H, rs, laneOK);
        h1 = lv_hrow(xi, yi, l++, cb, H, rs, laneOK);
        h2 = lv_hrow(xi, yi, l++, cb, H, rs, laneOK);
        h3 = lv_hrow(xi, yi, l++, cb, H, rs, laneOK);
        h4 = lv_hrow(xi, yi, l++, cb, H, rs, laneOK);
        h5 = lv_hrow(xi, yi, l++, cb, H, rs, laneOK);
        h6 = lv_hrow(xi, yi, l++, cb, H, rs, laneOK);
        h7 = lv_hrow(xi, yi, l++, cb, H, rs, laneOK);
        h8 = lv_hrow(xi, yi, l++, cb, H, rs, laneOK);
        h9 = lv_hrow(xi, yi, l++, cb, H, rs, laneOK);
    }
    float local = 0.f;
    {
        int l = R0 + 5, m = 0;
        for (int cc = 0; cc < nch; ++cc) {
            CHUNK(RSTEPL)
        }
    }

#pragma unroll
    for (int off = 32; off > 0; off >>= 1) local += __shfl_down(local, off, 64);
    if (lane == 0)
        atomicAdd(slots + ((long)lvl * NSLOT + (wid & (NSLOT - 1))) * SSTRIDE,
                  local);
}

__global__ void finalize_kernel(const float* __restrict__ slots,
                                float* __restrict__ out)
{
    const int t = threadIdx.x;
    const float w[5] = {0.0448f, 0.2856f, 0.3001f, 0.2363f, 0.1333f};
    const float wsum = w[0] + w[1] + w[2] + w[3] + w[4];
    float acc = 0.f;
#pragma unroll
    for (int lvl = 0; lvl < 5; ++lvl) {
        const int d = 512 >> lvl;
        const float cnt = (float)NIMG * (float)d * (float)d;
        acc += (w[lvl] / wsum) / cnt * slots[(lvl * NSLOT + t) * SSTRIDE];
    }
#pragma unroll
    for (int off = 32; off > 0; off >>= 1) acc += __shfl_down(acc, off, 64);
    __shared__ float pp[4];
    if ((t & 63) == 0) pp[t >> 6] = acc;
    __syncthreads();
    if (t == 0) out[0] = 1.0f - (pp[0] + pp[1] + pp[2] + pp[3]);
}

extern "C" void kernel_launch(void* const* d_in, const int* in_sizes, int n_in,
                              void* d_out, int out_size, void* d_ws, size_t ws_size,
                              hipStream_t stream)
{
    const float* pred = (const float*)d_in[0];
    const float* targ = (const float*)d_in[1];
    float* out = (float*)d_out;
    float* ws  = (float*)d_ws;

    float* slots = ws;                           // 5 * 256 * 16 floats (80 KB)
    float* zpad  = slots + 5 * NSLOT * SSTRIDE;  // 640 floats (layout compat)

    Pyr p;
    {
        float* b = zpad + 640;
        p.x1 = b + 8;                 b += NIMG * IS1;
        p.y1 = b + 8;                 b += NIMG * IS1;
        p.x2 = b + 8;                 b += NIMG * IS2;
        p.y2 = b + 8;                 b += NIMG * IS2;
        p.x3 = b + 8;                 b += NIMG * IS3;
        p.y3 = b + 8;                 b += NIMG * IS3;
        p.x4 = b + 8;                 b += NIMG * IS4;
        p.y4 = b + 8;
    }

    hipMemsetAsync(ws, 0, (size_t)(5 * NSLOT * SSTRIDE + 640) * sizeof(float),
                   stream);

    // L0 + fused pyramid: 3072 waves (12/CU)
    ssim_l0_stream<<<dim3(3072), 64, 0, stream>>>(pred, targ, p, slots);
    // L1-4: 1056 waves
    ssim_lvls_stream<<<dim3(1056), 64, 0, stream>>>(p, slots);

    finalize_kernel<<<1, 256, 0, stream>>>(slots, out);
}

// Round 8
// 344.328 us; speedup vs baseline: 3.9457x; 2.3795x over previous
//
#include <hip/hip_runtime.h>

// MS-SSIM loss, 5 levels.
// R18: ONE-LINE fix of R16/R17's spill: launch_bounds 2nd arg. Session
//   evidence: effective VGPR cap = 256/min_waves_per_EU on this
//   toolchain (R11 (,3)->84, R12 (,2)->128 clean, R16/R17 (,4)->64
//   spilled: WRITE 1.16GB scratch = 655us closed-form). Streaming
//   kernel needs ~110 live VGPRs -> (64,2) caps at 128; HW still runs
//   4 waves/SIMD at VGPR<=128 (50% occ ceiling). Everything else
//   identical to R17 (named-register ring, no LDS, no barriers,
//   64-thr blocks, pool phase at head).
//   Tripwire: if WRITE still >100MB at VGPR~128, live set >128 ->
//   trim ring next.
// Carried: channel-packed (x,y,xx+yy,xy) v4f conv; 11-deep NAMED ring
// (h0..h10, macro-rotated, zero indexing); padded pyramid (+8 col
// pads, zeroed by edge-strip waves); spread atomics; lane=own-column
// H (zero H recompute); pool via 8x8-patch + shfl tree.

#define NIMG 48
#define NSLOT 256
#define SSTRIDE 16             // 64 B between slots -> 1 cache line each

// padded pyramid geometry (8 zero cols each side)
#define RS1 272
#define RS2 144
#define RS3 80
#define RS4 48
#define IS0 (512L*512)
#define IS1 (256L*272)
#define IS2 (128L*144)
#define IS3 (64L*80)
#define IS4 (32L*48)

typedef float v4f __attribute__((ext_vector_type(4)));
typedef float uf4 __attribute__((ext_vector_type(4), aligned(4)));

struct Pyr { float *x1, *y1, *x2, *y2, *x3, *y3, *x4, *y4; };

#define GDEF const float G[11] = { \
    0.00102839f, 0.00759877f, 0.03600077f, 0.10936069f, 0.21300539f, \
    0.26601173f, 0.21300539f, 0.10936069f, 0.03600077f, 0.00759877f, \
    0.00102839f };

__device__ __forceinline__ void load12(const float* rp, int cb, float* w)
{
#pragma unroll
    for (int v = 0; v < 3; ++v) {
        const uf4 a = *reinterpret_cast<const uf4*>(rp + cb + 4 * v);
        w[4*v+0] = a.x; w[4*v+1] = a.y; w[4*v+2] = a.z; w[4*v+3] = a.w;
    }
}

__device__ __forceinline__ void load12g(const float* rp, int cb, int W, float* w)
{
#pragma unroll
    for (int e = 0; e < 12; ++e) {
        const int col = cb + e;
        w[e] = ((unsigned)col < (unsigned)W) ? rp[col] : 0.0f;
    }
}

// H-conv at this lane's col: v4f (x, y, xx+yy, xy)
__device__ __forceinline__ v4f h_of_row(const float* xw, const float* yw)
{
    GDEF
    v4f s = {0.f, 0.f, 0.f, 0.f};
#pragma unroll
    for (int k = 0; k < 11; ++k) {
        const float a = xw[k], b = yw[k];
        v4f w; w.x = a; w.y = b; w.z = a*a + b*b; w.w = a*b;
        s += w * G[k];                     // 2x v_pk_fma_f32
    }
    return s;
}

__device__ __forceinline__ float ssim_px(const v4f acc)
{
    const float C1 = 4.0e-4f;
    const float C2 = 3.6e-3f;
    const float mu1 = acc.x, mu2 = acc.y;
    const float mu1s = mu1*mu1, mu2s = mu2*mu2, m12 = mu1*mu2;
    const float ssum = acc.z - mu1s - mu2s;        // sig1+sig2
    const float s12  = acc.w - m12;
    const float num = (2.f * m12 + C1) * (2.f * s12 + C2);
    const float den = (mu1s + mu2s + C1) * (ssum + C2);
    return num * __builtin_amdgcn_rcpf(den + 1e-8f);
}

__device__ __forceinline__ v4f l0_hrow(const float* xi, const float* yi,
                                       int l, int cb, bool edge)
{
    float xw[12], yw[12];
    if ((unsigned)l < 512u) {
        const float* xr = xi + (long)l * 512;
        const float* yr = yi + (long)l * 512;
        if (!edge) { load12(xr, cb, xw); load12(yr, cb, yw); }
        else       { load12g(xr, cb, 512, xw); load12g(yr, cb, 512, yw); }
    } else {
#pragma unroll
        for (int e = 0; e < 12; ++e) { xw[e] = 0.f; yw[e] = 0.f; }
    }
    return h_of_row(xw, yw);
}

__device__ __forceinline__ v4f lv_hrow(const float* xi, const float* yi,
                                       int l, int cb, int H, int rs, bool laneOK)
{
    float xw[12], yw[12];
    if (((unsigned)l < (unsigned)H) && laneOK) {
        load12(xi + (long)l * rs, cb, xw);       // pads cover [-8, W+8)
        load12(yi + (long)l * rs, cb, yw);
    } else {
#pragma unroll
        for (int e = 0; e < 12; ++e) { xw[e] = 0.f; yw[e] = 0.f; }
    }
    return h_of_row(xw, yw);
}

// ring step macros: dst gets row l (the r+5 row); acc spans s0..s9,dst
#define RSTEP0(dst, s0,s1,s2,s3,s4,s5,s6,s7,s8,s9)                      \
    { dst = l0_hrow(xi, yi, l, cb, edge);                               \
      v4f acc = s0 * G[0];                                              \
      acc += s1*G[1]; acc += s2*G[2]; acc += s3*G[3]; acc += s4*G[4];   \
      acc += s5*G[5]; acc += s6*G[6]; acc += s7*G[7]; acc += s8*G[8];   \
      acc += s9*G[9]; acc += dst*G[10];                                 \
      if (m < 64) local += ssim_px(acc);                                \
      ++l; ++m; }

#define RSTEPL(dst, s0,s1,s2,s3,s4,s5,s6,s7,s8,s9)                      \
    { dst = lv_hrow(xi, yi, l, cb, H, rs, laneOK);                      \
      v4f acc = s0 * G[0];                                              \
      acc += s1*G[1]; acc += s2*G[2]; acc += s3*G[3]; acc += s4*G[4];   \
      acc += s5*G[5]; acc += s6*G[6]; acc += s7*G[7]; acc += s8*G[8];   \
      acc += s9*G[9]; acc += dst*G[10];                                 \
      if (m < mmax && laneOK) local += ssim_px(acc);                    \
      ++l; ++m; }

#define CHUNK(RS)                                   \
    RS(h10, h0,h1,h2,h3,h4,h5,h6,h7,h8,h9)          \
    RS(h0,  h1,h2,h3,h4,h5,h6,h7,h8,h9,h10)         \
    RS(h1,  h2,h3,h4,h5,h6,h7,h8,h9,h10,h0)         \
    RS(h2,  h3,h4,h5,h6,h7,h8,h9,h10,h0,h1)         \
    RS(h3,  h4,h5,h6,h7,h8,h9,h10,h0,h1,h2)         \
    RS(h4,  h5,h6,h7,h8,h9,h10,h0,h1,h2,h3)         \
    RS(h5,  h6,h7,h8,h9,h10,h0,h1,h2,h3,h4)         \
    RS(h6,  h7,h8,h9,h10,h0,h1,h2,h3,h4,h5)         \
    RS(h7,  h8,h9,h10,h0,h1,h2,h3,h4,h5,h6)         \
    RS(h8,  h9,h10,h0,h1,h2,h3,h4,h5,h6,h7)         \
    RS(h9,  h10,h0,h1,h2,h3,h4,h5,h6,h7,h8)

// ---- L0: pool (head) + streaming SSIM. 3072 blocks x 64 thr ----
__global__ __launch_bounds__(64, 2) void ssim_l0_stream(
    const float* __restrict__ x, const float* __restrict__ y,
    Pyr p, float* __restrict__ slots)
{
    GDEF
    const int lane  = threadIdx.x;
    const int wid   = blockIdx.x;
    const int R0    = (wid & 7) * 64;
    const int strip = (wid >> 3) & 7;
    const int C0    = strip * 64;
    const int z     = wid >> 6;
    const float* xi = x + (long)z * IS0;
    const float* yi = y + (long)z * IS0;
    const bool edge = (strip == 0) | (strip == 7);

    float* q1x = p.x1 + (long)z * IS1;  float* q1y = p.y1 + (long)z * IS1;
    float* q2x = p.x2 + (long)z * IS2;  float* q2y = p.y2 + (long)z * IS2;
    float* q3x = p.x3 + (long)z * IS3;  float* q3y = p.y3 + (long)z * IS3;
    float* q4x = p.x4 + (long)z * IS4;  float* q4y = p.y4 + (long)z * IS4;

    // ---- pool phase: lane owns an 8x8 patch of this 64x64 tile ----
    {
        const int r8 = lane >> 3, c8 = lane & 7;
        const int pr0 = R0 + 8 * r8, pc0 = C0 + 8 * c8;
        float x3x = 0.f, x3y = 0.f;
#pragma unroll
        for (int q2 = 0; q2 < 2; ++q2) {
            float sx0 = 0.f, sx1 = 0.f, sy0 = 0.f, sy1 = 0.f;
#pragma unroll
            for (int q1 = 0; q1 < 2; ++q1) {
                const int ir = pr0 + 4*q2 + 2*q1;
                const float* xr = xi + (long)ir * 512 + pc0;
                const float* yr = yi + (long)ir * 512 + pc0;
                const float4 a0 = *reinterpret_cast<const float4*>(xr);
                const float4 a1 = *reinterpret_cast<const float4*>(xr + 4);
                const float4 a2 = *reinterpret_cast<const float4*>(xr + 512);
                const float4 a3 = *reinterpret_cast<const float4*>(xr + 516);
                const float4 b0 = *reinterpret_cast<const float4*>(yr);
                const float4 b1 = *reinterpret_cast<const float4*>(yr + 4);
                const float4 b2 = *reinterpret_cast<const float4*>(yr + 512);
                const float4 b3 = *reinterpret_cast<const float4*>(yr + 516);
                const float qx0 = 0.25f*(a0.x+a0.y+a2.x+a2.y);
                const float qx1 = 0.25f*(a0.z+a0.w+a2.z+a2.w);
                const float qx2 = 0.25f*(a1.x+a1.y+a3.x+a3.y);
                const float qx3 = 0.25f*(a1.z+a1.w+a3.z+a3.w);
                const float qy0 = 0.25f*(b0.x+b0.y+b2.x+b2.y);
                const float qy1 = 0.25f*(b0.z+b0.w+b2.z+b2.w);
                const float qy2 = 0.25f*(b1.x+b1.y+b3.x+b3.y);
                const float qy3 = 0.25f*(b1.z+b1.w+b3.z+b3.w);
                float4 ox; ox.x=qx0; ox.y=qx1; ox.z=qx2; ox.w=qx3;
                float4 oy; oy.x=qy0; oy.y=qy1; oy.z=qy2; oy.w=qy3;
                *reinterpret_cast<float4*>(q1x + (long)(ir>>1)*RS1 + (pc0>>1)) = ox;
                *reinterpret_cast<float4*>(q1y + (long)(ir>>1)*RS1 + (pc0>>1)) = oy;
                sx0 += qx0+qx1; sx1 += qx2+qx3;
                sy0 += qy0+qy1; sy1 += qy2+qy3;
            }
            const float v2x0 = 0.25f*sx0, v2x1 = 0.25f*sx1;
            const float v2y0 = 0.25f*sy0, v2y1 = 0.25f*sy1;
            *reinterpret_cast<float2*>(q2x + (long)((pr0>>2)+q2)*RS2 + (pc0>>2))
                = make_float2(v2x0, v2x1);
            *reinterpret_cast<float2*>(q2y + (long)((pr0>>2)+q2)*RS2 + (pc0>>2))
                = make_float2(v2y0, v2y1);
            x3x += v2x0+v2x1; x3y += v2y0+v2y1;
        }
        x3x *= 0.25f; x3y *= 0.25f;
        q3x[(long)(pr0>>3)*RS3 + (pc0>>3)] = x3x;
        q3y[(long)(pr0>>3)*RS3 + (pc0>>3)] = x3y;
        const float v4x = 0.25f*(x3x + __shfl_down(x3x,1,64)
                               + __shfl_down(x3x,8,64) + __shfl_down(x3x,9,64));
        const float v4y = 0.25f*(x3y + __shfl_down(x3y,1,64)
                               + __shfl_down(x3y,8,64) + __shfl_down(x3y,9,64));
        if (!(r8 & 1) && !(c8 & 1)) {
            q4x[(long)(pr0>>4)*RS4 + (pc0>>4)] = v4x;
            q4y[(long)(pr0>>4)*RS4 + (pc0>>4)] = v4y;
        }
        // zero the 8-col pads of all levels (edge strips only)
        if (edge) {
            const bool left = (strip == 0);
            const int p1c = left ? (c8 - 8) : (256 + c8);
            const int p2c = left ? (c8 - 8) : (128 + c8);
            const int p3c = left ? (c8 - 8) : (64 + c8);
            const int p4c = left ? (c8 - 8) : (32 + c8);
#pragma unroll
            for (int i = 0; i < 4; ++i) {
                const int rr = (R0>>1) + 8*i + r8;
                q1x[(long)rr*RS1 + p1c] = 0.f; q1y[(long)rr*RS1 + p1c] = 0.f;
            }
#pragma unroll
            for (int i = 0; i < 2; ++i) {
                const int rr = (R0>>2) + 8*i + r8;
                q2x[(long)rr*RS2 + p2c] = 0.f; q2y[(long)rr*RS2 + p2c] = 0.f;
            }
            { const int rr = (R0>>3) + r8;
              q3x[(long)rr*RS3 + p3c] = 0.f; q3y[(long)rr*RS3 + p3c] = 0.f; }
            if (r8 < 4) {
                const int rr = (R0>>4) + r8;
                q4x[(long)rr*RS4 + p4c] = 0.f; q4y[(long)rr*RS4 + p4c] = 0.f;
            }
        }
    }

    // ---- streaming SSIM: 11-deep named-register ring ----
    const int cb = C0 + lane - 5;
    v4f h0,h1,h2,h3,h4,h5,h6,h7,h8,h9,h10;
    {
        int l = R0 - 5;
        h0 = l0_hrow(xi, yi, l++, cb, edge);
        h1 = l0_hrow(xi, yi, l++, cb, edge);
        h2 = l0_hrow(xi, yi, l++, cb, edge);
        h3 = l0_hrow(xi, yi, l++, cb, edge);
        h4 = l0_hrow(xi, yi, l++, cb, edge);
        h5 = l0_hrow(xi, yi, l++, cb, edge);
        h6 = l0_hrow(xi, yi, l++, cb, edge);
        h7 = l0_hrow(xi, yi, l++, cb, edge);
        h8 = l0_hrow(xi, yi, l++, cb, edge);
        h9 = l0_hrow(xi, yi, l++, cb, edge);
    }
    float local = 0.f;
    {
        int l = R0 + 5, m = 0;
        for (int cc = 0; cc < 6; ++cc) {
            CHUNK(RSTEP0)
        }
    }

#pragma unroll
    for (int off = 32; off > 0; off >>= 1) local += __shfl_down(local, off, 64);
    if (lane == 0) atomicAdd(slots + (wid & (NSLOT - 1)) * SSTRIDE, local);
}

// ---- levels 1-4, streaming. 1056 blocks x 64 thr ----
__global__ __launch_bounds__(64, 2) void ssim_lvls_stream(
    Pyr p, float* __restrict__ slots)
{
    GDEF
    const int lane = threadIdx.x;
    const int wid  = blockIdx.x;

    const float* xi; const float* yi;
    int rs, H, W, C0, R0, lvl;
    if (wid < 768) {
        lvl = 1; const int r = wid & 15, z = wid >> 4;
        xi = p.x1 + (long)z * IS1; yi = p.y1 + (long)z * IS1;
        rs = RS1; H = W = 256; C0 = (r & 3) * 64; R0 = (r >> 2) * 64;
    } else if (wid < 960) {
        lvl = 2; const int w2 = wid - 768; const int r = w2 & 3, z = w2 >> 2;
        xi = p.x2 + (long)z * IS2; yi = p.y2 + (long)z * IS2;
        rs = RS2; H = W = 128; C0 = (r & 1) * 64; R0 = ((r >> 1) & 1) * 64;
    } else if (wid < 1008) {
        lvl = 3; const int z = wid - 960;
        xi = p.x3 + (long)z * IS3; yi = p.y3 + (long)z * IS3;
        rs = RS3; H = W = 64; C0 = 0; R0 = 0;
    } else {
        lvl = 4; const int z = wid - 1008;
        xi = p.x4 + (long)z * IS4; yi = p.y4 + (long)z * IS4;
        rs = RS4; H = W = 32; C0 = 0; R0 = 0;
    }
    const int cb = C0 + lane - 5;
    const bool laneOK = (C0 + lane) < W;
    const int mmax = (H - R0 < 64) ? (H - R0) : 64;
    const int nch  = (mmax + 10) / 11;

    v4f h0,h1,h2,h3,h4,h5,h6,h7,h8,h9,h10;
    {
        int l = R0 - 5;
        h0 = lv_hrow(xi, yi, l++, cb, H, rs, laneOK);
        h1 = lv_hrow(xi, yi, l++, cb, H, rs, laneOK);
        h2 = lv_hrow(xi, yi, l++, cb, H, rs, laneOK);
        h3 = lv_hrow(xi, yi, l++, cb, H, rs, laneOK);
        h4 = lv_hrow(xi, yi, l++, cb, H, rs, laneOK);
        h5 = lv_hrow(xi, yi, l++, cb, H, rs, laneOK);
        h6 = lv_hrow(xi, yi, l++, cb, H, rs, laneOK);
        h7 = lv_hrow(xi, yi, l++, cb, H, rs, laneOK);
        h8 = lv_hrow(xi, yi, l++, cb, H, rs, laneOK);
        h9 = lv_hrow(xi, yi, l++, cb, H, rs, laneOK);
    }
    float local = 0.f;
    {
        int l = R0 + 5, m = 0;
        for (int cc = 0; cc < nch; ++cc) {
            CHUNK(RSTEPL)
        }
    }

#pragma unroll
    for (int off = 32; off > 0; off >>= 1) local += __shfl_down(local, off, 64);
    if (lane == 0)
        atomicAdd(slots + ((long)lvl * NSLOT + (wid & (NSLOT - 1))) * SSTRIDE,
                  local);
}

__global__ void finalize_kernel(const float* __restrict__ slots,
                                float* __restrict__ out)
{
    const int t = threadIdx.x;
    const float w[5] = {0.0448f, 0.2856f, 0.3001f, 0.2363f, 0.1333f};
    const float wsum = w[0] + w[1] + w[2] + w[3] + w[4];
    float acc = 0.f;
#pragma unroll
    for (int lvl = 0; lvl < 5; ++lvl) {
        const int d = 512 >> lvl;
        const float cnt = (float)NIMG * (float)d * (float)d;
        acc += (w[lvl] / wsum) / cnt * slots[(lvl * NSLOT + t) * SSTRIDE];
    }
#pragma unroll
    for (int off = 32; off > 0; off >>= 1) acc += __shfl_down(acc, off, 64);
    __shared__ float pp[4];
    if ((t & 63) == 0) pp[t >> 6] = acc;
    __syncthreads();
    if (t == 0) out[0] = 1.0f - (pp[0] + pp[1] + pp[2] + pp[3]);
}

extern "C" void kernel_launch(void* const* d_in, const int* in_sizes, int n_in,
                              void* d_out, int out_size, void* d_ws, size_t ws_size,
                              hipStream_t stream)
{
    const float* pred = (const float*)d_in[0];
    const float* targ = (const float*)d_in[1];
    float* out = (float*)d_out;
    float* ws  = (float*)d_ws;

    float* slots = ws;                           // 5 * 256 * 16 floats (80 KB)
    float* zpad  = slots + 5 * NSLOT * SSTRIDE;  // 640 floats (layout compat)

    Pyr p;
    {
        float* b = zpad + 640;
        p.x1 = b + 8;                 b += NIMG * IS1;
        p.y1 = b + 8;                 b += NIMG * IS1;
        p.x2 = b + 8;                 b += NIMG * IS2;
        p.y2 = b + 8;                 b += NIMG * IS2;
        p.x3 = b + 8;                 b += NIMG * IS3;
        p.y3 = b + 8;                 b += NIMG * IS3;
        p.x4 = b + 8;                 b += NIMG * IS4;
        p.y4 = b + 8;
    }

    hipMemsetAsync(ws, 0, (size_t)(5 * NSLOT * SSTRIDE + 640) * sizeof(float),
                   stream);

    // L0 + fused pyramid: 3072 waves
    ssim_l0_stream<<<dim3(3072), 64, 0, stream>>>(pred, targ, p, slots);
    // L1-4: 1056 waves
    ssim_lvls_stream<<<dim3(1056), 64, 0, stream>>>(p, slots);

    finalize_kernel<<<1, 256, 0, stream>>>(slots, out);
}

// Round 9
// 343.830 us; speedup vs baseline: 3.9514x; 1.0014x over previous
//
#include <hip/hip_runtime.h>

// MS-SSIM loss, 5 levels.
// R19: stop the unroll-induced spill. Post-mortem R18: (64,2) cap=128
//   worked (VGPR 128, dur 655->205us) but WRITE 142MB vs 36MB pyramid
//   => ~106MB residual scratch. Cause: `for(cc<6){CHUNK}` is a const-
//   trip loop of an 11-step macro with NO stores in the body -- the
//   compiler fully unrolls to 66 steps and hoists global_loads across
//   steps without bound, blowing the 128 cap; RA spills the ring
//   (longest reuse distance). Fix: #pragma unroll 1 on the chunk loops
//   (both kernels). Rotation is identity after 11 steps so the named
//   ring is loop-carried cleanly. Live set back to ~85-105 <= 128.
//   Tripwire: WRITE ~37MB. If still >100MB, hoisting theory wrong ->
//   next round reads disasm (-save-temps, count scratch_store).
// Carried: effective VGPR cap = 256/min_waves_per_EU (R16-R18 ladder);
// channel-packed (x,y,xx+yy,xy) v4f conv; 11-deep NAMED ring (h0..h10,
// macro-rotated, zero indexing); no LDS, no barriers; 64-thr blocks
// (tile math in SGPRs); pool phase at head w/ shfl tree; padded
// pyramid (+8 col pads, edge-zeroed); spread atomics.

#define NIMG 48
#define NSLOT 256
#define SSTRIDE 16             // 64 B between slots -> 1 cache line each

// padded pyramid geometry (8 zero cols each side)
#define RS1 272
#define RS2 144
#define RS3 80
#define RS4 48
#define IS0 (512L*512)
#define IS1 (256L*272)
#define IS2 (128L*144)
#define IS3 (64L*80)
#define IS4 (32L*48)

typedef float v4f __attribute__((ext_vector_type(4)));
typedef float uf4 __attribute__((ext_vector_type(4), aligned(4)));

struct Pyr { float *x1, *y1, *x2, *y2, *x3, *y3, *x4, *y4; };

#define GDEF const float G[11] = { \
    0.00102839f, 0.00759877f, 0.03600077f, 0.10936069f, 0.21300539f, \
    0.26601173f, 0.21300539f, 0.10936069f, 0.03600077f, 0.00759877f, \
    0.00102839f };

__device__ __forceinline__ void load12(const float* rp, int cb, float* w)
{
#pragma unroll
    for (int v = 0; v < 3; ++v) {
        const uf4 a = *reinterpret_cast<const uf4*>(rp + cb + 4 * v);
        w[4*v+0] = a.x; w[4*v+1] = a.y; w[4*v+2] = a.z; w[4*v+3] = a.w;
    }
}

__device__ __forceinline__ void load12g(const float* rp, int cb, int W, float* w)
{
#pragma unroll
    for (int e = 0; e < 12; ++e) {
        const int col = cb + e;
        w[e] = ((unsigned)col < (unsigned)W) ? rp[col] : 0.0f;
    }
}

// H-conv at this lane's col: v4f (x, y, xx+yy, xy)
__device__ __forceinline__ v4f h_of_row(const float* xw, const float* yw)
{
    GDEF
    v4f s = {0.f, 0.f, 0.f, 0.f};
#pragma unroll
    for (int k = 0; k < 11; ++k) {
        const float a = xw[k], b = yw[k];
        v4f w; w.x = a; w.y = b; w.z = a*a + b*b; w.w = a*b;
        s += w * G[k];                     // 2x v_pk_fma_f32
    }
    return s;
}

__device__ __forceinline__ float ssim_px(const v4f acc)
{
    const float C1 = 4.0e-4f;
    const float C2 = 3.6e-3f;
    const float mu1 = acc.x, mu2 = acc.y;
    const float mu1s = mu1*mu1, mu2s = mu2*mu2, m12 = mu1*mu2;
    const float ssum = acc.z - mu1s - mu2s;        // sig1+sig2
    const float s12  = acc.w - m12;
    const float num = (2.f * m12 + C1) * (2.f * s12 + C2);
    const float den = (mu1s + mu2s + C1) * (ssum + C2);
    return num * __builtin_amdgcn_rcpf(den + 1e-8f);
}

__device__ __forceinline__ v4f l0_hrow(const float* xi, const float* yi,
                                       int l, int cb, bool edge)
{
    float xw[12], yw[12];
    if ((unsigned)l < 512u) {
        const float* xr = xi + (long)l * 512;
        const float* yr = yi + (long)l * 512;
        if (!edge) { load12(xr, cb, xw); load12(yr, cb, yw); }
        else       { load12g(xr, cb, 512, xw); load12g(yr, cb, 512, yw); }
    } else {
#pragma unroll
        for (int e = 0; e < 12; ++e) { xw[e] = 0.f; yw[e] = 0.f; }
    }
    return h_of_row(xw, yw);
}

__device__ __forceinline__ v4f lv_hrow(const float* xi, const float* yi,
                                       int l, int cb, int H, int rs, bool laneOK)
{
    float xw[12], yw[12];
    if (((unsigned)l < (unsigned)H) && laneOK) {
        load12(xi + (long)l * rs, cb, xw);       // pads cover [-8, W+8)
        load12(yi + (long)l * rs, cb, yw);
    } else {
#pragma unroll
        for (int e = 0; e < 12; ++e) { xw[e] = 0.f; yw[e] = 0.f; }
    }
    return h_of_row(xw, yw);
}

// ring step macros: dst gets row l (the r+5 row); acc spans s0..s9,dst
#define RSTEP0(dst, s0,s1,s2,s3,s4,s5,s6,s7,s8,s9)                      \
    { dst = l0_hrow(xi, yi, l, cb, edge);                               \
      v4f acc = s0 * G[0];                                              \
      acc += s1*G[1]; acc += s2*G[2]; acc += s3*G[3]; acc += s4*G[4];   \
      acc += s5*G[5]; acc += s6*G[6]; acc += s7*G[7]; acc += s8*G[8];   \
      acc += s9*G[9]; acc += dst*G[10];                                 \
      if (m < 64) local += ssim_px(acc);                                \
      ++l; ++m; }

#define RSTEPL(dst, s0,s1,s2,s3,s4,s5,s6,s7,s8,s9)                      \
    { dst = lv_hrow(xi, yi, l, cb, H, rs, laneOK);                      \
      v4f acc = s0 * G[0];                                              \
      acc += s1*G[1]; acc += s2*G[2]; acc += s3*G[3]; acc += s4*G[4];   \
      acc += s5*G[5]; acc += s6*G[6]; acc += s7*G[7]; acc += s8*G[8];   \
      acc += s9*G[9]; acc += dst*G[10];                                 \
      if (m < mmax && laneOK) local += ssim_px(acc);                    \
      ++l; ++m; }

#define CHUNK(RS)                                   \
    RS(h10, h0,h1,h2,h3,h4,h5,h6,h7,h8,h9)          \
    RS(h0,  h1,h2,h3,h4,h5,h6,h7,h8,h9,h10)         \
    RS(h1,  h2,h3,h4,h5,h6,h7,h8,h9,h10,h0)         \
    RS(h2,  h3,h4,h5,h6,h7,h8,h9,h10,h0,h1)         \
    RS(h3,  h4,h5,h6,h7,h8,h9,h10,h0,h1,h2)         \
    RS(h4,  h5,h6,h7,h8,h9,h10,h0,h1,h2,h3)         \
    RS(h5,  h6,h7,h8,h9,h10,h0,h1,h2,h3,h4)         \
    RS(h6,  h7,h8,h9,h10,h0,h1,h2,h3,h4,h5)         \
    RS(h7,  h8,h9,h10,h0,h1,h2,h3,h4,h5,h6)         \
    RS(h8,  h9,h10,h0,h1,h2,h3,h4,h5,h6,h7)         \
    RS(h9,  h10,h0,h1,h2,h3,h4,h5,h6,h7,h8)

// ---- L0: pool (head) + streaming SSIM. 3072 blocks x 64 thr ----
__global__ __launch_bounds__(64, 2) void ssim_l0_stream(
    const float* __restrict__ x, const float* __restrict__ y,
    Pyr p, float* __restrict__ slots)
{
    GDEF
    const int lane  = threadIdx.x;
    const int wid   = blockIdx.x;
    const int R0    = (wid & 7) * 64;
    const int strip = (wid >> 3) & 7;
    const int C0    = strip * 64;
    const int z     = wid >> 6;
    const float* xi = x + (long)z * IS0;
    const float* yi = y + (long)z * IS0;
    const bool edge = (strip == 0) | (strip == 7);

    float* q1x = p.x1 + (long)z * IS1;  float* q1y = p.y1 + (long)z * IS1;
    float* q2x = p.x2 + (long)z * IS2;  float* q2y = p.y2 + (long)z * IS2;
    float* q3x = p.x3 + (long)z * IS3;  float* q3y = p.y3 + (long)z * IS3;
    float* q4x = p.x4 + (long)z * IS4;  float* q4y = p.y4 + (long)z * IS4;

    // ---- pool phase: lane owns an 8x8 patch of this 64x64 tile ----
    {
        const int r8 = lane >> 3, c8 = lane & 7;
        const int pr0 = R0 + 8 * r8, pc0 = C0 + 8 * c8;
        float x3x = 0.f, x3y = 0.f;
#pragma unroll
        for (int q2 = 0; q2 < 2; ++q2) {
            float sx0 = 0.f, sx1 = 0.f, sy0 = 0.f, sy1 = 0.f;
#pragma unroll
            for (int q1 = 0; q1 < 2; ++q1) {
                const int ir = pr0 + 4*q2 + 2*q1;
                const float* xr = xi + (long)ir * 512 + pc0;
                const float* yr = yi + (long)ir * 512 + pc0;
                const float4 a0 = *reinterpret_cast<const float4*>(xr);
                const float4 a1 = *reinterpret_cast<const float4*>(xr + 4);
                const float4 a2 = *reinterpret_cast<const float4*>(xr + 512);
                const float4 a3 = *reinterpret_cast<const float4*>(xr + 516);
                const float4 b0 = *reinterpret_cast<const float4*>(yr);
                const float4 b1 = *reinterpret_cast<const float4*>(yr + 4);
                const float4 b2 = *reinterpret_cast<const float4*>(yr + 512);
                const float4 b3 = *reinterpret_cast<const float4*>(yr + 516);
                const float qx0 = 0.25f*(a0.x+a0.y+a2.x+a2.y);
                const float qx1 = 0.25f*(a0.z+a0.w+a2.z+a2.w);
                const float qx2 = 0.25f*(a1.x+a1.y+a3.x+a3.y);
                const float qx3 = 0.25f*(a1.z+a1.w+a3.z+a3.w);
                const float qy0 = 0.25f*(b0.x+b0.y+b2.x+b2.y);
                const float qy1 = 0.25f*(b0.z+b0.w+b2.z+b2.w);
                const float qy2 = 0.25f*(b1.x+b1.y+b3.x+b3.y);
                const float qy3 = 0.25f*(b1.z+b1.w+b3.z+b3.w);
                float4 ox; ox.x=qx0; ox.y=qx1; ox.z=qx2; ox.w=qx3;
                float4 oy; oy.x=qy0; oy.y=qy1; oy.z=qy2; oy.w=qy3;
                *reinterpret_cast<float4*>(q1x + (long)(ir>>1)*RS1 + (pc0>>1)) = ox;
                *reinterpret_cast<float4*>(q1y + (long)(ir>>1)*RS1 + (pc0>>1)) = oy;
                sx0 += qx0+qx1; sx1 += qx2+qx3;
                sy0 += qy0+qy1; sy1 += qy2+qy3;
            }
            const float v2x0 = 0.25f*sx0, v2x1 = 0.25f*sx1;
            const float v2y0 = 0.25f*sy0, v2y1 = 0.25f*sy1;
            *reinterpret_cast<float2*>(q2x + (long)((pr0>>2)+q2)*RS2 + (pc0>>2))
                = make_float2(v2x0, v2x1);
            *reinterpret_cast<float2*>(q2y + (long)((pr0>>2)+q2)*RS2 + (pc0>>2))
                = make_float2(v2y0, v2y1);
            x3x += v2x0+v2x1; x3y += v2y0+v2y1;
        }
        x3x *= 0.25f; x3y *= 0.25f;
        q3x[(long)(pr0>>3)*RS3 + (pc0>>3)] = x3x;
        q3y[(long)(pr0>>3)*RS3 + (pc0>>3)] = x3y;
        const float v4x = 0.25f*(x3x + __shfl_down(x3x,1,64)
                               + __shfl_down(x3x,8,64) + __shfl_down(x3x,9,64));
        const float v4y = 0.25f*(x3y + __shfl_down(x3y,1,64)
                               + __shfl_down(x3y,8,64) + __shfl_down(x3y,9,64));
        if (!(r8 & 1) && !(c8 & 1)) {
            q4x[(long)(pr0>>4)*RS4 + (pc0>>4)] = v4x;
            q4y[(long)(pr0>>4)*RS4 + (pc0>>4)] = v4y;
        }
        // zero the 8-col pads of all levels (edge strips only)
        if (edge) {
            const bool left = (strip == 0);
            const int p1c = left ? (c8 - 8) : (256 + c8);
            const int p2c = left ? (c8 - 8) : (128 + c8);
            const int p3c = left ? (c8 - 8) : (64 + c8);
            const int p4c = left ? (c8 - 8) : (32 + c8);
#pragma unroll
            for (int i = 0; i < 4; ++i) {
                const int rr = (R0>>1) + 8*i + r8;
                q1x[(long)rr*RS1 + p1c] = 0.f; q1y[(long)rr*RS1 + p1c] = 0.f;
            }
#pragma unroll
            for (int i = 0; i < 2; ++i) {
                const int rr = (R0>>2) + 8*i + r8;
                q2x[(long)rr*RS2 + p2c] = 0.f; q2y[(long)rr*RS2 + p2c] = 0.f;
            }
            { const int rr = (R0>>3) + r8;
              q3x[(long)rr*RS3 + p3c] = 0.f; q3y[(long)rr*RS3 + p3c] = 0.f; }
            if (r8 < 4) {
                const int rr = (R0>>4) + r8;
                q4x[(long)rr*RS4 + p4c] = 0.f; q4y[(long)rr*RS4 + p4c] = 0.f;
            }
        }
    }

    // ---- streaming SSIM: 11-deep named-register ring ----
    const int cb = C0 + lane - 5;
    v4f h0,h1,h2,h3,h4,h5,h6,h7,h8,h9,h10;
    {
        int l = R0 - 5;
        h0 = l0_hrow(xi, yi, l++, cb, edge);
        h1 = l0_hrow(xi, yi, l++, cb, edge);
        h2 = l0_hrow(xi, yi, l++, cb, edge);
        h3 = l0_hrow(xi, yi, l++, cb, edge);
        h4 = l0_hrow(xi, yi, l++, cb, edge);
        h5 = l0_hrow(xi, yi, l++, cb, edge);
        h6 = l0_hrow(xi, yi, l++, cb, edge);
        h7 = l0_hrow(xi, yi, l++, cb, edge);
        h8 = l0_hrow(xi, yi, l++, cb, edge);
        h9 = l0_hrow(xi, yi, l++, cb, edge);
    }
    float local = 0.f;
    {
        int l = R0 + 5, m = 0;
#pragma unroll 1
        for (int cc = 0; cc < 6; ++cc) {     // unroll 1: bound load hoisting
            CHUNK(RSTEP0)
        }
    }

#pragma unroll
    for (int off = 32; off > 0; off >>= 1) local += __shfl_down(local, off, 64);
    if (lane == 0) atomicAdd(slots + (wid & (NSLOT - 1)) * SSTRIDE, local);
}

// ---- levels 1-4, streaming. 1056 blocks x 64 thr ----
__global__ __launch_bounds__(64, 2) void ssim_lvls_stream(
    Pyr p, float* __restrict__ slots)
{
    GDEF
    const int lane = threadIdx.x;
    const int wid  = blockIdx.x;

    const float* xi; const float* yi;
    int rs, H, W, C0, R0, lvl;
    if (wid < 768) {
        lvl = 1; const int r = wid & 15, z = wid >> 4;
        xi = p.x1 + (long)z * IS1; yi = p.y1 + (long)z * IS1;
        rs = RS1; H = W = 256; C0 = (r & 3) * 64; R0 = (r >> 2) * 64;
    } else if (wid < 960) {
        lvl = 2; const int w2 = wid - 768; const int r = w2 & 3, z = w2 >> 2;
        xi = p.x2 + (long)z * IS2; yi = p.y2 + (long)z * IS2;
        rs = RS2; H = W = 128; C0 = (r & 1) * 64; R0 = ((r >> 1) & 1) * 64;
    } else if (wid < 1008) {
        lvl = 3; const int z = wid - 960;
        xi = p.x3 + (long)z * IS3; yi = p.y3 + (long)z * IS3;
        rs = RS3; H = W = 64; C0 = 0; R0 = 0;
    } else {
        lvl = 4; const int z = wid - 1008;
        xi = p.x4 + (long)z * IS4; yi = p.y4 + (long)z * IS4;
        rs = RS4; H = W = 32; C0 = 0; R0 = 0;
    }
    const int cb = C0 + lane - 5;
    const bool laneOK = (C0 + lane) < W;
    const int mmax = (H - R0 < 64) ? (H - R0) : 64;
    const int nch  = (mmax + 10) / 11;

    v4f h0,h1,h2,h3,h4,h5,h6,h7,h8,h9,h10;
    {
        int l = R0 - 5;
        h0 = lv_hrow(xi, yi, l++, cb, H, rs, laneOK);
        h1 = lv_hrow(xi, yi, l++, cb, H, rs, laneOK);
        h2 = lv_hrow(xi, yi, l++, cb, H, rs, laneOK);
        h3 = lv_hrow(xi, yi, l++, cb, H, rs, laneOK);
        h4 = lv_hrow(xi, yi, l++, cb, H, rs, laneOK);
        h5 = lv_hrow(xi, yi, l++, cb, H, rs, laneOK);
        h6 = lv_hrow(xi, yi, l++, cb, H, rs, laneOK);
        h7 = lv_hrow(xi, yi, l++, cb, H, rs, laneOK);
        h8 = lv_hrow(xi, yi, l++, cb, H, rs, laneOK);
        h9 = lv_hrow(xi, yi, l++, cb, H, rs, laneOK);
    }
    float local = 0.f;
    {
        int l = R0 + 5, m = 0;
#pragma unroll 1
        for (int cc = 0; cc < nch; ++cc) {   // unroll 1: bound load hoisting
            CHUNK(RSTEPL)
        }
    }

#pragma unroll
    for (int off = 32; off > 0; off >>= 1) local += __shfl_down(local, off, 64);
    if (lane == 0)
        atomicAdd(slots + ((long)lvl * NSLOT + (wid & (NSLOT - 1))) * SSTRIDE,
                  local);
}

__global__ void finalize_kernel(const float* __restrict__ slots,
                                float* __restrict__ out)
{
    const int t = threadIdx.x;
    const float w[5] = {0.0448f, 0.2856f, 0.3001f, 0.2363f, 0.1333f};
    const float wsum = w[0] + w[1] + w[2] + w[3] + w[4];
    float acc = 0.f;
#pragma unroll
    for (int lvl = 0; lvl < 5; ++lvl) {
        const int d = 512 >> lvl;
        const float cnt = (float)NIMG * (float)d * (float)d;
        acc += (w[lvl] / wsum) / cnt * slots[(lvl * NSLOT + t) * SSTRIDE];
    }
#pragma unroll
    for (int off = 32; off > 0; off >>= 1) acc += __shfl_down(acc, off, 64);
    __shared__ float pp[4];
    if ((t & 63) == 0) pp[t >> 6] = acc;
    __syncthreads();
    if (t == 0) out[0] = 1.0f - (pp[0] + pp[1] + pp[2] + pp[3]);
}

extern "C" void kernel_launch(void* const* d_in, const int* in_sizes, int n_in,
                              void* d_out, int out_size, void* d_ws, size_t ws_size,
                              hipStream_t stream)
{
    const float* pred = (const float*)d_in[0];
    const float* targ = (const float*)d_in[1];
    float* out = (float*)d_out;
    float* ws  = (float*)d_ws;

    float* slots = ws;                           // 5 * 256 * 16 floats (80 KB)
    float* zpad  = slots + 5 * NSLOT * SSTRIDE;  // 640 floats (layout compat)

    Pyr p;
    {
        float* b = zpad + 640;
        p.x1 = b + 8;                 b += NIMG * IS1;
        p.y1 = b + 8;                 b += NIMG * IS1;
        p.x2 = b + 8;                 b += NIMG * IS2;
        p.y2 = b + 8;                 b += NIMG * IS2;
        p.x3 = b + 8;                 b += NIMG * IS3;
        p.y3 = b + 8;                 b += NIMG * IS3;
        p.x4 = b + 8;                 b += NIMG * IS4;
        p.y4 = b + 8;
    }

    hipMemsetAsync(ws, 0, (size_t)(5 * NSLOT * SSTRIDE + 640) * sizeof(float),
                   stream);

    // L0 + fused pyramid: 3072 waves
    ssim_l0_stream<<<dim3(3072), 64, 0, stream>>>(pred, targ, p, slots);
    // L1-4: 1056 waves
    ssim_lvls_stream<<<dim3(1056), 64, 0, stream>>>(p, slots);

    finalize_kernel<<<1, 256, 0, stream>>>(slots, out);
}

// Round 10
// 295.169 us; speedup vs baseline: 4.6028x; 1.1649x over previous
//
#include <hip/hip_runtime.h>

// MS-SSIM loss, 5 levels.
// R20: LDS ring, single-wave blocks, zero barriers, zero scratch.
//   Post-mortem R19: unroll-1 changed NOTHING (VGPR 128, WRITE 142MB
//   identical) -> hoisting is WITHIN straight-line regions (10-step
//   prologue, 11-step CHUNK body), not across the loop. Register ring
//   (44 VGPR, longest reuse distance) is what RA evicts; 135 spilled
//   floats/lane matches one prologue over-subscription. Fix category:
//   ring moves to LDS (11x64xv4f = 11264B). Single-wave blocks need NO
//   barriers (intra-wave ds ordering via lgkmcnt). VGPR live ~80
//   (ping-pong windows only) -> no spill; 14 blocks/CU LDS cap; also
//   tests whether scratch backing was the session's residency cap.
//   Structure: rolled prologue (real back-edge stops load batching),
//   2-step ping-pong prefetch (xwa/xwb, zero copies), V-conv reads 11
//   LDS slots/step, sched_barrier(0) between pool and stream phases.
//   Tripwires: WRITE ~37MB (spill), occupancy (scratch-residency
//   discriminator).
// Carried: effective VGPR cap = 256/min_waves_per_EU (R16-R18);
// channel-packed (x,y,xx+yy,xy) v4f; 64-thr blocks (tile math in
// SGPRs); pool phase at head w/ shfl tree; padded pyramid (+8 col
// pads, edge-zeroed); spread atomics; lane=own-column H.

#define NIMG 48
#define NSLOT 256
#define SSTRIDE 16             // 64 B between slots -> 1 cache line each

// padded pyramid geometry (8 zero cols each side)
#define RS1 272
#define RS2 144
#define RS3 80
#define RS4 48
#define IS0 (512L*512)
#define IS1 (256L*272)
#define IS2 (128L*144)
#define IS3 (64L*80)
#define IS4 (32L*48)

typedef float v4f __attribute__((ext_vector_type(4)));
typedef float uf4 __attribute__((ext_vector_type(4), aligned(4)));

struct Pyr { float *x1, *y1, *x2, *y2, *x3, *y3, *x4, *y4; };

#define GDEF const float G[11] = { \
    0.00102839f, 0.00759877f, 0.03600077f, 0.10936069f, 0.21300539f, \
    0.26601173f, 0.21300539f, 0.10936069f, 0.03600077f, 0.00759877f, \
    0.00102839f };

#define WRAP11(v) (((v) + 1 == 11) ? 0 : (v) + 1)

__device__ __forceinline__ void load12(const float* rp, int cb, float* w)
{
#pragma unroll
    for (int v = 0; v < 3; ++v) {
        const uf4 a = *reinterpret_cast<const uf4*>(rp + cb + 4 * v);
        w[4*v+0] = a.x; w[4*v+1] = a.y; w[4*v+2] = a.z; w[4*v+3] = a.w;
    }
}

__device__ __forceinline__ void load12g(const float* rp, int cb, int W, float* w)
{
#pragma unroll
    for (int e = 0; e < 12; ++e) {
        const int col = cb + e;
        w[e] = ((unsigned)col < (unsigned)W) ? rp[col] : 0.0f;
    }
}

// L0 window load (row l, cols [cb, cb+12)) with edge/row guards
__device__ __forceinline__ void l0_win(const float* xi, const float* yi,
                                       int l, int cb, bool edge,
                                       float* xw, float* yw)
{
    if ((unsigned)l < 512u) {
        const float* xr = xi + (long)l * 512;
        const float* yr = yi + (long)l * 512;
        if (!edge) { load12(xr, cb, xw); load12(yr, cb, yw); }
        else       { load12g(xr, cb, 512, xw); load12g(yr, cb, 512, yw); }
    } else {
#pragma unroll
        for (int e = 0; e < 12; ++e) { xw[e] = 0.f; yw[e] = 0.f; }
    }
}

// pyramid-level window load (col pads cover [-8, W+8))
__device__ __forceinline__ void lv_win(const float* xi, const float* yi,
                                       int l, int cb, int H, int rs,
                                       bool laneOK, float* xw, float* yw)
{
    if (((unsigned)l < (unsigned)H) && laneOK) {
        load12(xi + (long)l * rs, cb, xw);
        load12(yi + (long)l * rs, cb, yw);
    } else {
#pragma unroll
        for (int e = 0; e < 12; ++e) { xw[e] = 0.f; yw[e] = 0.f; }
    }
}

// H-conv at this lane's col: v4f (x, y, xx+yy, xy)
__device__ __forceinline__ v4f h_of_row(const float* xw, const float* yw)
{
    GDEF
    v4f s = {0.f, 0.f, 0.f, 0.f};
#pragma unroll
    for (int k = 0; k < 11; ++k) {
        const float a = xw[k], b = yw[k];
        v4f w; w.x = a; w.y = b; w.z = a*a + b*b; w.w = a*b;
        s += w * G[k];                     // 2x v_pk_fma_f32
    }
    return s;
}

__device__ __forceinline__ float ssim_px(const v4f acc)
{
    const float C1 = 4.0e-4f;
    const float C2 = 3.6e-3f;
    const float mu1 = acc.x, mu2 = acc.y;
    const float mu1s = mu1*mu1, mu2s = mu2*mu2, m12 = mu1*mu2;
    const float ssum = acc.z - mu1s - mu2s;        // sig1+sig2
    const float s12  = acc.w - m12;
    const float num = (2.f * m12 + C1) * (2.f * s12 + C2);
    const float den = (mu1s + mu2s + C1) * (ssum + C2);
    return num * __builtin_amdgcn_rcpf(den + 1e-8f);
}

// V-conv over 11 LDS ring slots starting at vb
__device__ __forceinline__ float vconv(const v4f (*ring)[64], int vb, int lane)
{
    GDEF
    v4f acc = {0.f, 0.f, 0.f, 0.f};
    int sl = vb;
#pragma unroll
    for (int k = 0; k < 11; ++k) {
        acc += ring[sl][lane] * G[k];      // ds_read_b128 + 2 pk_fma
        sl = WRAP11(sl);
    }
    return ssim_px(acc);
}

// ---- L0: pool (head) + streaming SSIM. 3072 blocks x 64 thr ----
__global__ __launch_bounds__(64, 2) void ssim_l0_stream(
    const float* __restrict__ x, const float* __restrict__ y,
    Pyr p, float* __restrict__ slots)
{
    __shared__ __align__(16) v4f ring[11][64];     // 11264 B

    const int lane  = threadIdx.x;
    const int wid   = blockIdx.x;
    const int R0    = (wid & 7) * 64;
    const int strip = (wid >> 3) & 7;
    const int C0    = strip * 64;
    const int z     = wid >> 6;
    const float* xi = x + (long)z * IS0;
    const float* yi = y + (long)z * IS0;
    const bool edge = (strip == 0) | (strip == 7);

    float* q1x = p.x1 + (long)z * IS1;  float* q1y = p.y1 + (long)z * IS1;
    float* q2x = p.x2 + (long)z * IS2;  float* q2y = p.y2 + (long)z * IS2;
    float* q3x = p.x3 + (long)z * IS3;  float* q3y = p.y3 + (long)z * IS3;
    float* q4x = p.x4 + (long)z * IS4;  float* q4y = p.y4 + (long)z * IS4;

    // ---- pool phase: lane owns an 8x8 patch of this 64x64 tile ----
    {
        const int r8 = lane >> 3, c8 = lane & 7;
        const int pr0 = R0 + 8 * r8, pc0 = C0 + 8 * c8;
        float x3x = 0.f, x3y = 0.f;
#pragma unroll
        for (int q2 = 0; q2 < 2; ++q2) {
            float sx0 = 0.f, sx1 = 0.f, sy0 = 0.f, sy1 = 0.f;
#pragma unroll
            for (int q1 = 0; q1 < 2; ++q1) {
                const int ir = pr0 + 4*q2 + 2*q1;
                const float* xr = xi + (long)ir * 512 + pc0;
                const float* yr = yi + (long)ir * 512 + pc0;
                const float4 a0 = *reinterpret_cast<const float4*>(xr);
                const float4 a1 = *reinterpret_cast<const float4*>(xr + 4);
                const float4 a2 = *reinterpret_cast<const float4*>(xr + 512);
                const float4 a3 = *reinterpret_cast<const float4*>(xr + 516);
                const float4 b0 = *reinterpret_cast<const float4*>(yr);
                const float4 b1 = *reinterpret_cast<const float4*>(yr + 4);
                const float4 b2 = *reinterpret_cast<const float4*>(yr + 512);
                const float4 b3 = *reinterpret_cast<const float4*>(yr + 516);
                const float qx0 = 0.25f*(a0.x+a0.y+a2.x+a2.y);
                const float qx1 = 0.25f*(a0.z+a0.w+a2.z+a2.w);
                const float qx2 = 0.25f*(a1.x+a1.y+a3.x+a3.y);
                const float qx3 = 0.25f*(a1.z+a1.w+a3.z+a3.w);
                const float qy0 = 0.25f*(b0.x+b0.y+b2.x+b2.y);
                const float qy1 = 0.25f*(b0.z+b0.w+b2.z+b2.w);
                const float qy2 = 0.25f*(b1.x+b1.y+b3.x+b3.y);
                const float qy3 = 0.25f*(b1.z+b1.w+b3.z+b3.w);
                float4 ox; ox.x=qx0; ox.y=qx1; ox.z=qx2; ox.w=qx3;
                float4 oy; oy.x=qy0; oy.y=qy1; oy.z=qy2; oy.w=qy3;
                *reinterpret_cast<float4*>(q1x + (long)(ir>>1)*RS1 + (pc0>>1)) = ox;
                *reinterpret_cast<float4*>(q1y + (long)(ir>>1)*RS1 + (pc0>>1)) = oy;
                sx0 += qx0+qx1; sx1 += qx2+qx3;
                sy0 += qy0+qy1; sy1 += qy2+qy3;
            }
            const float v2x0 = 0.25f*sx0, v2x1 = 0.25f*sx1;
            const float v2y0 = 0.25f*sy0, v2y1 = 0.25f*sy1;
            *reinterpret_cast<float2*>(q2x + (long)((pr0>>2)+q2)*RS2 + (pc0>>2))
                = make_float2(v2x0, v2x1);
            *reinterpret_cast<float2*>(q2y + (long)((pr0>>2)+q2)*RS2 + (pc0>>2))
                = make_float2(v2y0, v2y1);
            x3x += v2x0+v2x1; x3y += v2y0+v2y1;
        }
        x3x *= 0.25f; x3y *= 0.25f;
        q3x[(long)(pr0>>3)*RS3 + (pc0>>3)] = x3x;
        q3y[(long)(pr0>>3)*RS3 + (pc0>>3)] = x3y;
        const float v4x = 0.25f*(x3x + __shfl_down(x3x,1,64)
                               + __shfl_down(x3x,8,64) + __shfl_down(x3x,9,64));
        const float v4y = 0.25f*(x3y + __shfl_down(x3y,1,64)
                               + __shfl_down(x3y,8,64) + __shfl_down(x3y,9,64));
        if (!(r8 & 1) && !(c8 & 1)) {
            q4x[(long)(pr0>>4)*RS4 + (pc0>>4)] = v4x;
            q4y[(long)(pr0>>4)*RS4 + (pc0>>4)] = v4y;
        }
        // zero the 8-col pads of all levels (edge strips only)
        if (edge) {
            const bool left = (strip == 0);
            const int p1c = left ? (c8 - 8) : (256 + c8);
            const int p2c = left ? (c8 - 8) : (128 + c8);
            const int p3c = left ? (c8 - 8) : (64 + c8);
            const int p4c = left ? (c8 - 8) : (32 + c8);
#pragma unroll
            for (int i = 0; i < 4; ++i) {
                const int rr = (R0>>1) + 8*i + r8;
                q1x[(long)rr*RS1 + p1c] = 0.f; q1y[(long)rr*RS1 + p1c] = 0.f;
            }
#pragma unroll
            for (int i = 0; i < 2; ++i) {
                const int rr = (R0>>2) + 8*i + r8;
                q2x[(long)rr*RS2 + p2c] = 0.f; q2y[(long)rr*RS2 + p2c] = 0.f;
            }
            { const int rr = (R0>>3) + r8;
              q3x[(long)rr*RS3 + p3c] = 0.f; q3y[(long)rr*RS3 + p3c] = 0.f; }
            if (r8 < 4) {
                const int rr = (R0>>4) + r8;
                q4x[(long)rr*RS4 + p4c] = 0.f; q4y[(long)rr*RS4 + p4c] = 0.f;
            }
        }
    }
    __builtin_amdgcn_sched_barrier(0);   // keep stream loads out of pool phase

    // ---- streaming SSIM: LDS ring, ping-pong register prefetch ----
    const int cb = C0 + lane - 5;
    float local = 0.f;

    // prologue: rows R0-5 .. R0+4 -> slots 0..9 (rolled: bounds hoisting)
#pragma unroll 1
    for (int s = 0; s < 10; ++s) {
        float xw[12], yw[12];
        l0_win(xi, yi, R0 - 5 + s, cb, edge, xw, yw);
        ring[s][lane] = h_of_row(xw, yw);
    }

    float xwa[12], ywa[12], xwb[12], ywb[12];
    l0_win(xi, yi, R0 + 5, cb, edge, xwa, ywa);    // prefetch row R0+5
    int wslot = 10, vb = 0, lload = R0 + 6;
#pragma unroll 1
    for (int pp = 0; pp < 32; ++pp) {
        // step A: consume a, prefetch b
        ring[wslot][lane] = h_of_row(xwa, ywa);
        l0_win(xi, yi, lload, cb, edge, xwb, ywb); ++lload;
        local += vconv(ring, vb, lane);
        wslot = WRAP11(wslot); vb = WRAP11(vb);
        // step B: consume b, prefetch a
        ring[wslot][lane] = h_of_row(xwb, ywb);
        l0_win(xi, yi, lload, cb, edge, xwa, ywa); ++lload;
        local += vconv(ring, vb, lane);
        wslot = WRAP11(wslot); vb = WRAP11(vb);
    }

#pragma unroll
    for (int off = 32; off > 0; off >>= 1) local += __shfl_down(local, off, 64);
    if (lane == 0) atomicAdd(slots + (wid & (NSLOT - 1)) * SSTRIDE, local);
}

// ---- levels 1-4, streaming. 1056 blocks x 64 thr ----
__global__ __launch_bounds__(64, 2) void ssim_lvls_stream(
    Pyr p, float* __restrict__ slots)
{
    __shared__ __align__(16) v4f ring[11][64];

    const int lane = threadIdx.x;
    const int wid  = blockIdx.x;

    const float* xi; const float* yi;
    int rs, H, W, C0, R0, lvl;
    if (wid < 768) {
        lvl = 1; const int r = wid & 15, z = wid >> 4;
        xi = p.x1 + (long)z * IS1; yi = p.y1 + (long)z * IS1;
        rs = RS1; H = W = 256; C0 = (r & 3) * 64; R0 = (r >> 2) * 64;
    } else if (wid < 960) {
        lvl = 2; const int w2 = wid - 768; const int r = w2 & 3, z = w2 >> 2;
        xi = p.x2 + (long)z * IS2; yi = p.y2 + (long)z * IS2;
        rs = RS2; H = W = 128; C0 = (r & 1) * 64; R0 = ((r >> 1) & 1) * 64;
    } else if (wid < 1008) {
        lvl = 3; const int z = wid - 960;
        xi = p.x3 + (long)z * IS3; yi = p.y3 + (long)z * IS3;
        rs = RS3; H = W = 64; C0 = 0; R0 = 0;
    } else {
        lvl = 4; const int z = wid - 1008;
        xi = p.x4 + (long)z * IS4; yi = p.y4 + (long)z * IS4;
        rs = RS4; H = W = 32; C0 = 0; R0 = 0;
    }
    const int cb = C0 + lane - 5;
    const bool laneOK = (C0 + lane) < W;
    const int mmax = (H - R0 < 64) ? (H - R0) : 64;
    const int npairs = mmax >> 1;
    float local = 0.f;

#pragma unroll 1
    for (int s = 0; s < 10; ++s) {
        float xw[12], yw[12];
        lv_win(xi, yi, R0 - 5 + s, cb, H, rs, laneOK, xw, yw);
        ring[s][lane] = h_of_row(xw, yw);
    }

    float xwa[12], ywa[12], xwb[12], ywb[12];
    lv_win(xi, yi, R0 + 5, cb, H, rs, laneOK, xwa, ywa);
    int wslot = 10, vb = 0, lload = R0 + 6;
#pragma unroll 1
    for (int pp = 0; pp < npairs; ++pp) {
        ring[wslot][lane] = h_of_row(xwa, ywa);
        lv_win(xi, yi, lload, cb, H, rs, laneOK, xwb, ywb); ++lload;
        if (laneOK) local += vconv(ring, vb, lane);
        wslot = WRAP11(wslot); vb = WRAP11(vb);
        ring[wslot][lane] = h_of_row(xwb, ywb);
        lv_win(xi, yi, lload, cb, H, rs, laneOK, xwa, ywa); ++lload;
        if (laneOK) local += vconv(ring, vb, lane);
        wslot = WRAP11(wslot); vb = WRAP11(vb);
    }

#pragma unroll
    for (int off = 32; off > 0; off >>= 1) local += __shfl_down(local, off, 64);
    if (lane == 0)
        atomicAdd(slots + ((long)lvl * NSLOT + (wid & (NSLOT - 1))) * SSTRIDE,
                  local);
}

__global__ void finalize_kernel(const float* __restrict__ slots,
                                float* __restrict__ out)
{
    const int t = threadIdx.x;
    const float w[5] = {0.0448f, 0.2856f, 0.3001f, 0.2363f, 0.1333f};
    const float wsum = w[0] + w[1] + w[2] + w[3] + w[4];
    float acc = 0.f;
#pragma unroll
    for (int lvl = 0; lvl < 5; ++lvl) {
        const int d = 512 >> lvl;
        const float cnt = (float)NIMG * (float)d * (float)d;
        acc += (w[lvl] / wsum) / cnt * slots[(lvl * NSLOT + t) * SSTRIDE];
    }
#pragma unroll
    for (int off = 32; off > 0; off >>= 1) acc += __shfl_down(acc, off, 64);
    __shared__ float pp[4];
    if ((t & 63) == 0) pp[t >> 6] = acc;
    __syncthreads();
    if (t == 0) out[0] = 1.0f - (pp[0] + pp[1] + pp[2] + pp[3]);
}

extern "C" void kernel_launch(void* const* d_in, const int* in_sizes, int n_in,
                              void* d_out, int out_size, void* d_ws, size_t ws_size,
                              hipStream_t stream)
{
    const float* pred = (const float*)d_in[0];
    const float* targ = (const float*)d_in[1];
    float* out = (float*)d_out;
    float* ws  = (float*)d_ws;

    float* slots = ws;                           // 5 * 256 * 16 floats (80 KB)
    float* zpad  = slots + 5 * NSLOT * SSTRIDE;  // 640 floats (layout compat)

    Pyr p;
    {
        float* b = zpad + 640;
        p.x1 = b + 8;                 b += NIMG * IS1;
        p.y1 = b + 8;                 b += NIMG * IS1;
        p.x2 = b + 8;                 b += NIMG * IS2;
        p.y2 = b + 8;                 b += NIMG * IS2;
        p.x3 = b + 8;                 b += NIMG * IS3;
        p.y3 = b + 8;                 b += NIMG * IS3;
        p.x4 = b + 8;                 b += NIMG * IS4;
        p.y4 = b + 8;
    }

    hipMemsetAsync(ws, 0, (size_t)(5 * NSLOT * SSTRIDE + 640) * sizeof(float),
                   stream);

    // L0 + fused pyramid: 3072 single-wave blocks (12 waves/CU)
    ssim_l0_stream<<<dim3(3072), 64, 0, stream>>>(pred, targ, p, slots);
    // L1-4: 1056 single-wave blocks
    ssim_lvls_stream<<<dim3(1056), 64, 0, stream>>>(p, slots);

    finalize_kernel<<<1, 256, 0, stream>>>(slots, out);
}

// Round 11
// 273.013 us; speedup vs baseline: 4.9764x; 1.0812x over previous
//
#include <hip/hip_runtime.h>

// MS-SSIM loss, 5 levels.
// R21: supply the waves. Post-mortem R20: spill GONE (WRITE 142->41MB,
//   VGPR 60, LDS ring works barrier-free in single-wave blocks) and
//   VALUBusy 28->44%; but occ 25% = 8 waves/CU because the grid only
//   offers 12 blocks/CU (LDS cap 14, VGPR headroom 8/SIMD). Latency
//   half-hidden at 2 waves/SIMD. Fix: 32-row bands -> L0 6144 blocks
//   (24/CU eligible, saturates the 14 LDS cap with backfill), lvls
//   2064. Cost: +13% H-row work (10-row prologue per 32 rows). All
//   bands now exactly tile every level (no tail guards). Pool tree
//   re-derived for 64x32 tiles (lane = 8x4 patch; x3 shfl_down 8,
//   x4 shfl_down 1/16/17).
//   Tripwires: occ ~40% expected; if it pins low again with supply
//   present, residency cap is elsewhere -> disasm + micro-probe.
// Carried: LDS ring 11x64xv4f (11264B), ping-pong 1-row-ahead
// prefetch, rolled prologue, single-wave blocks (no barriers,
// lgkmcnt-ordered); launch_bounds(64,2) [VGPR cap = 256/minwaves];
// channel-packed (x,y,xx+yy,xy); padded pyramid + edge-zeroed pads;
// spread atomics; lane=own-column H.

#define NIMG 48
#define NSLOT 256
#define SSTRIDE 16             // 64 B between slots -> 1 cache line each

// padded pyramid geometry (8 zero cols each side)
#define RS1 272
#define RS2 144
#define RS3 80
#define RS4 48
#define IS0 (512L*512)
#define IS1 (256L*272)
#define IS2 (128L*144)
#define IS3 (64L*80)
#define IS4 (32L*48)

typedef float v4f __attribute__((ext_vector_type(4)));
typedef float uf4 __attribute__((ext_vector_type(4), aligned(4)));

struct Pyr { float *x1, *y1, *x2, *y2, *x3, *y3, *x4, *y4; };

#define GDEF const float G[11] = { \
    0.00102839f, 0.00759877f, 0.03600077f, 0.10936069f, 0.21300539f, \
    0.26601173f, 0.21300539f, 0.10936069f, 0.03600077f, 0.00759877f, \
    0.00102839f };

#define WRAP11(v) (((v) + 1 == 11) ? 0 : (v) + 1)

__device__ __forceinline__ void load12(const float* rp, int cb, float* w)
{
#pragma unroll
    for (int v = 0; v < 3; ++v) {
        const uf4 a = *reinterpret_cast<const uf4*>(rp + cb + 4 * v);
        w[4*v+0] = a.x; w[4*v+1] = a.y; w[4*v+2] = a.z; w[4*v+3] = a.w;
    }
}

__device__ __forceinline__ void load12g(const float* rp, int cb, int W, float* w)
{
#pragma unroll
    for (int e = 0; e < 12; ++e) {
        const int col = cb + e;
        w[e] = ((unsigned)col < (unsigned)W) ? rp[col] : 0.0f;
    }
}

// L0 window load (row l, cols [cb, cb+12)) with edge/row guards
__device__ __forceinline__ void l0_win(const float* xi, const float* yi,
                                       int l, int cb, bool edge,
                                       float* xw, float* yw)
{
    if ((unsigned)l < 512u) {
        const float* xr = xi + (long)l * 512;
        const float* yr = yi + (long)l * 512;
        if (!edge) { load12(xr, cb, xw); load12(yr, cb, yw); }
        else       { load12g(xr, cb, 512, xw); load12g(yr, cb, 512, yw); }
    } else {
#pragma unroll
        for (int e = 0; e < 12; ++e) { xw[e] = 0.f; yw[e] = 0.f; }
    }
}

// pyramid-level window load (col pads cover [-8, W+8))
__device__ __forceinline__ void lv_win(const float* xi, const float* yi,
                                       int l, int cb, int H, int rs,
                                       bool laneOK, float* xw, float* yw)
{
    if (((unsigned)l < (unsigned)H) && laneOK) {
        load12(xi + (long)l * rs, cb, xw);
        load12(yi + (long)l * rs, cb, yw);
    } else {
#pragma unroll
        for (int e = 0; e < 12; ++e) { xw[e] = 0.f; yw[e] = 0.f; }
    }
}

// H-conv at this lane's col: v4f (x, y, xx+yy, xy)
__device__ __forceinline__ v4f h_of_row(const float* xw, const float* yw)
{
    GDEF
    v4f s = {0.f, 0.f, 0.f, 0.f};
#pragma unroll
    for (int k = 0; k < 11; ++k) {
        const float a = xw[k], b = yw[k];
        v4f w; w.x = a; w.y = b; w.z = a*a + b*b; w.w = a*b;
        s += w * G[k];                     // 2x v_pk_fma_f32
    }
    return s;
}

__device__ __forceinline__ float ssim_px(const v4f acc)
{
    const float C1 = 4.0e-4f;
    const float C2 = 3.6e-3f;
    const float mu1 = acc.x, mu2 = acc.y;
    const float mu1s = mu1*mu1, mu2s = mu2*mu2, m12 = mu1*mu2;
    const float ssum = acc.z - mu1s - mu2s;        // sig1+sig2
    const float s12  = acc.w - m12;
    const float num = (2.f * m12 + C1) * (2.f * s12 + C2);
    const float den = (mu1s + mu2s + C1) * (ssum + C2);
    return num * __builtin_amdgcn_rcpf(den + 1e-8f);
}

// V-conv over 11 LDS ring slots starting at vb
__device__ __forceinline__ float vconv(const v4f (*ring)[64], int vb, int lane)
{
    GDEF
    v4f acc = {0.f, 0.f, 0.f, 0.f};
    int sl = vb;
#pragma unroll
    for (int k = 0; k < 11; ++k) {
        acc += ring[sl][lane] * G[k];      // ds_read_b128 + 2 pk_fma
        sl = WRAP11(sl);
    }
    return ssim_px(acc);
}

// ---- L0: pool (head) + streaming SSIM. 6144 blocks x 64 thr ----
// wid: band = wid&15 (32 rows), strip = (wid>>4)&7 (64 cols), z = wid>>7.
__global__ __launch_bounds__(64, 2) void ssim_l0_stream(
    const float* __restrict__ x, const float* __restrict__ y,
    Pyr p, float* __restrict__ slots)
{
    __shared__ __align__(16) v4f ring[11][64];     // 11264 B -> 14 blocks/CU

    const int lane  = threadIdx.x;
    const int wid   = blockIdx.x;
    const int R0    = (wid & 15) * 32;
    const int strip = (wid >> 4) & 7;
    const int C0    = strip * 64;
    const int z     = wid >> 7;
    const float* xi = x + (long)z * IS0;
    const float* yi = y + (long)z * IS0;
    const bool edge = (strip == 0) | (strip == 7);

    float* q1x = p.x1 + (long)z * IS1;  float* q1y = p.y1 + (long)z * IS1;
    float* q2x = p.x2 + (long)z * IS2;  float* q2y = p.y2 + (long)z * IS2;
    float* q3x = p.x3 + (long)z * IS3;  float* q3y = p.y3 + (long)z * IS3;
    float* q4x = p.x4 + (long)z * IS4;  float* q4y = p.y4 + (long)z * IS4;

    // ---- pool phase: lane owns an 8-col x 4-row patch of the 64x32 tile ----
    {
        const int r8 = lane >> 3, c8 = lane & 7;
        const int pr0 = R0 + 4 * r8, pc0 = C0 + 8 * c8;
        float v2x0, v2x1, v2y0, v2y1;
        {
            float sx0 = 0.f, sx1 = 0.f, sy0 = 0.f, sy1 = 0.f;
#pragma unroll
            for (int rp = 0; rp < 2; ++rp) {       // row pairs (0,1), (2,3)
                const int ir = pr0 + 2 * rp;
                const float* xr = xi + (long)ir * 512 + pc0;
                const float* yr = yi + (long)ir * 512 + pc0;
                const float4 a0 = *reinterpret_cast<const float4*>(xr);
                const float4 a1 = *reinterpret_cast<const float4*>(xr + 4);
                const float4 a2 = *reinterpret_cast<const float4*>(xr + 512);
                const float4 a3 = *reinterpret_cast<const float4*>(xr + 516);
                const float4 b0 = *reinterpret_cast<const float4*>(yr);
                const float4 b1 = *reinterpret_cast<const float4*>(yr + 4);
                const float4 b2 = *reinterpret_cast<const float4*>(yr + 512);
                const float4 b3 = *reinterpret_cast<const float4*>(yr + 516);
                const float qx0 = 0.25f*(a0.x+a0.y+a2.x+a2.y);
                const float qx1 = 0.25f*(a0.z+a0.w+a2.z+a2.w);
                const float qx2 = 0.25f*(a1.x+a1.y+a3.x+a3.y);
                const float qx3 = 0.25f*(a1.z+a1.w+a3.z+a3.w);
                const float qy0 = 0.25f*(b0.x+b0.y+b2.x+b2.y);
                const float qy1 = 0.25f*(b0.z+b0.w+b2.z+b2.w);
                const float qy2 = 0.25f*(b1.x+b1.y+b3.x+b3.y);
                const float qy3 = 0.25f*(b1.z+b1.w+b3.z+b3.w);
                float4 ox; ox.x=qx0; ox.y=qx1; ox.z=qx2; ox.w=qx3;
                float4 oy; oy.x=qy0; oy.y=qy1; oy.z=qy2; oy.w=qy3;
                const int r1 = (R0 >> 1) + 2*r8 + rp;
                *reinterpret_cast<float4*>(q1x + (long)r1*RS1 + (pc0>>1)) = ox;
                *reinterpret_cast<float4*>(q1y + (long)r1*RS1 + (pc0>>1)) = oy;
                sx0 += qx0+qx1; sx1 += qx2+qx3;
                sy0 += qy0+qy1; sy1 += qy2+qy3;
            }
            v2x0 = 0.25f*sx0; v2x1 = 0.25f*sx1;
            v2y0 = 0.25f*sy0; v2y1 = 0.25f*sy1;
            *reinterpret_cast<float2*>(q2x + (long)((R0>>2)+r8)*RS2 + (pc0>>2))
                = make_float2(v2x0, v2x1);
            *reinterpret_cast<float2*>(q2y + (long)((R0>>2)+r8)*RS2 + (pc0>>2))
                = make_float2(v2y0, v2y1);
        }
        // x3: rows pair via lane+8 (r8 pair), cols within-lane
        const float s3x = v2x0 + v2x1, s3y = v2y0 + v2y1;
        const float v3x = 0.25f*(s3x + __shfl_down(s3x, 8, 64));
        const float v3y = 0.25f*(s3y + __shfl_down(s3y, 8, 64));
        if (!(r8 & 1)) {
            q3x[(long)((R0>>3)+(r8>>1))*RS3 + (C0>>3)+c8] = v3x;
            q3y[(long)((R0>>3)+(r8>>1))*RS3 + (C0>>3)+c8] = v3y;
        }
        // x4: x3 quad {lane, lane+1, lane+16, lane+17}
        const float v4x = 0.25f*(v3x + __shfl_down(v3x,1,64)
                               + __shfl_down(v3x,16,64) + __shfl_down(v3x,17,64));
        const float v4y = 0.25f*(v3y + __shfl_down(v3y,1,64)
                               + __shfl_down(v3y,16,64) + __shfl_down(v3y,17,64));
        if (!(r8 & 3) && !(c8 & 1)) {
            q4x[(long)((R0>>4)+(r8>>2))*RS4 + (C0>>4)+(c8>>1)] = v4x;
            q4y[(long)((R0>>4)+(r8>>2))*RS4 + (C0>>4)+(c8>>1)] = v4y;
        }
        // zero the 8-col pads of all levels (edge strips only)
        if (edge) {
            const bool left = (strip == 0);
            const int p1c = left ? (c8 - 8) : (256 + c8);
            const int p2c = left ? (c8 - 8) : (128 + c8);
            const int p3c = left ? (c8 - 8) : (64 + c8);
            const int p4c = left ? (c8 - 8) : (32 + c8);
#pragma unroll
            for (int i = 0; i < 2; ++i) {          // x1: 16 pad rows
                const int rr = (R0>>1) + 8*i + r8;
                q1x[(long)rr*RS1 + p1c] = 0.f; q1y[(long)rr*RS1 + p1c] = 0.f;
            }
            { const int rr = (R0>>2) + r8;         // x2: 8 pad rows
              q2x[(long)rr*RS2 + p2c] = 0.f; q2y[(long)rr*RS2 + p2c] = 0.f; }
            if (r8 < 4) {                          // x3: 4 pad rows
                const int rr = (R0>>3) + r8;
                q3x[(long)rr*RS3 + p3c] = 0.f; q3y[(long)rr*RS3 + p3c] = 0.f;
            }
            if (r8 < 2) {                          // x4: 2 pad rows
                const int rr = (R0>>4) + r8;
                q4x[(long)rr*RS4 + p4c] = 0.f; q4y[(long)rr*RS4 + p4c] = 0.f;
            }
        }
    }
    __builtin_amdgcn_sched_barrier(0);   // keep stream loads out of pool phase

    // ---- streaming SSIM: LDS ring, ping-pong register prefetch ----
    const int cb = C0 + lane - 5;
    float local = 0.f;

    // prologue: rows R0-5 .. R0+4 -> slots 0..9 (rolled: bounds hoisting)
#pragma unroll 1
    for (int s = 0; s < 10; ++s) {
        float xw[12], yw[12];
        l0_win(xi, yi, R0 - 5 + s, cb, edge, xw, yw);
        ring[s][lane] = h_of_row(xw, yw);
    }

    float xwa[12], ywa[12], xwb[12], ywb[12];
    l0_win(xi, yi, R0 + 5, cb, edge, xwa, ywa);    // prefetch row R0+5
    int wslot = 10, vb = 0, lload = R0 + 6;
#pragma unroll 1
    for (int pp = 0; pp < 16; ++pp) {              // 32 output rows
        ring[wslot][lane] = h_of_row(xwa, ywa);
        l0_win(xi, yi, lload, cb, edge, xwb, ywb); ++lload;
        local += vconv(ring, vb, lane);
        wslot = WRAP11(wslot); vb = WRAP11(vb);
        ring[wslot][lane] = h_of_row(xwb, ywb);
        l0_win(xi, yi, lload, cb, edge, xwa, ywa); ++lload;
        local += vconv(ring, vb, lane);
        wslot = WRAP11(wslot); vb = WRAP11(vb);
    }

#pragma unroll
    for (int off = 32; off > 0; off >>= 1) local += __shfl_down(local, off, 64);
    if (lane == 0) atomicAdd(slots + (wid & (NSLOT - 1)) * SSTRIDE, local);
}

// ---- levels 1-4, streaming, 32-row bands. 2064 blocks x 64 thr ----
// L1: 4 strips x 8 bands x 48 = 1536; L2: 2x4x48 = 384;
// L3: 1x2x48 = 96; L4: 48.
__global__ __launch_bounds__(64, 2) void ssim_lvls_stream(
    Pyr p, float* __restrict__ slots)
{
    __shared__ __align__(16) v4f ring[11][64];

    const int lane = threadIdx.x;
    const int wid  = blockIdx.x;

    const float* xi; const float* yi;
    int rs, H, W, C0, R0, lvl;
    if (wid < 1536) {
        lvl = 1; const int r = wid & 31, z = wid >> 5;
        xi = p.x1 + (long)z * IS1; yi = p.y1 + (long)z * IS1;
        rs = RS1; H = W = 256; C0 = (r & 3) * 64; R0 = (r >> 2) * 32;
    } else if (wid < 1920) {
        lvl = 2; const int w2 = wid - 1536; const int r = w2 & 7, z = w2 >> 3;
        xi = p.x2 + (long)z * IS2; yi = p.y2 + (long)z * IS2;
        rs = RS2; H = W = 128; C0 = (r & 1) * 64; R0 = (r >> 1) * 32;
    } else if (wid < 2016) {
        lvl = 3; const int w2 = wid - 1920; const int by = w2 & 1, z = w2 >> 1;
        xi = p.x3 + (long)z * IS3; yi = p.y3 + (long)z * IS3;
        rs = RS3; H = W = 64; C0 = 0; R0 = by * 32;
    } else {
        lvl = 4; const int z = wid - 2016;
        xi = p.x4 + (long)z * IS4; yi = p.y4 + (long)z * IS4;
        rs = RS4; H = W = 32; C0 = 0; R0 = 0;
    }
    const int cb = C0 + lane - 5;
    const bool laneOK = (C0 + lane) < W;
    float local = 0.f;

#pragma unroll 1
    for (int s = 0; s < 10; ++s) {
        float xw[12], yw[12];
        lv_win(xi, yi, R0 - 5 + s, cb, H, rs, laneOK, xw, yw);
        ring[s][lane] = h_of_row(xw, yw);
    }

    float xwa[12], ywa[12], xwb[12], ywb[12];
    lv_win(xi, yi, R0 + 5, cb, H, rs, laneOK, xwa, ywa);
    int wslot = 10, vb = 0, lload = R0 + 6;
#pragma unroll 1
    for (int pp = 0; pp < 16; ++pp) {              // 32 output rows
        ring[wslot][lane] = h_of_row(xwa, ywa);
        lv_win(xi, yi, lload, cb, H, rs, laneOK, xwb, ywb); ++lload;
        if (laneOK) local += vconv(ring, vb, lane);
        wslot = WRAP11(wslot); vb = WRAP11(vb);
        ring[wslot][lane] = h_of_row(xwb, ywb);
        lv_win(xi, yi, lload, cb, H, rs, laneOK, xwa, ywa); ++lload;
        if (laneOK) local += vconv(ring, vb, lane);
        wslot = WRAP11(wslot); vb = WRAP11(vb);
    }

#pragma unroll
    for (int off = 32; off > 0; off >>= 1) local += __shfl_down(local, off, 64);
    if (lane == 0)
        atomicAdd(slots + ((long)lvl * NSLOT + (wid & (NSLOT - 1))) * SSTRIDE,
                  local);
}

__global__ void finalize_kernel(const float* __restrict__ slots,
                                float* __restrict__ out)
{
    const int t = threadIdx.x;
    const float w[5] = {0.0448f, 0.2856f, 0.3001f, 0.2363f, 0.1333f};
    const float wsum = w[0] + w[1] + w[2] + w[3] + w[4];
    float acc = 0.f;
#pragma unroll
    for (int lvl = 0; lvl < 5; ++lvl) {
        const int d = 512 >> lvl;
        const float cnt = (float)NIMG * (float)d * (float)d;
        acc += (w[lvl] / wsum) / cnt * slots[(lvl * NSLOT + t) * SSTRIDE];
    }
#pragma unroll
    for (int off = 32; off > 0; off >>= 1) acc += __shfl_down(acc, off, 64);
    __shared__ float pp[4];
    if ((t & 63) == 0) pp[t >> 6] = acc;
    __syncthreads();
    if (t == 0) out[0] = 1.0f - (pp[0] + pp[1] + pp[2] + pp[3]);
}

extern "C" void kernel_launch(void* const* d_in, const int* in_sizes, int n_in,
                              void* d_out, int out_size, void* d_ws, size_t ws_size,
                              hipStream_t stream)
{
    const float* pred = (const float*)d_in[0];
    const float* targ = (const float*)d_in[1];
    float* out = (float*)d_out;
    float* ws  = (float*)d_ws;

    float* slots = ws;                           // 5 * 256 * 16 floats (80 KB)
    float* zpad  = slots + 5 * NSLOT * SSTRIDE;  // 640 floats (layout compat)

    Pyr p;
    {
        float* b = zpad + 640;
        p.x1 = b + 8;                 b += NIMG * IS1;
        p.y1 = b + 8;                 b += NIMG * IS1;
        p.x2 = b + 8;                 b += NIMG * IS2;
        p.y2 = b + 8;                 b += NIMG * IS2;
        p.x3 = b + 8;                 b += NIMG * IS3;
        p.y3 = b + 8;                 b += NIMG * IS3;
        p.x4 = b + 8;                 b += NIMG * IS4;
        p.y4 = b + 8;
    }

    hipMemsetAsync(ws, 0, (size_t)(5 * NSLOT * SSTRIDE + 640) * sizeof(float),
                   stream);

    // L0 + fused pyramid: 6144 single-wave blocks (24/CU eligible, 14 cap)
    ssim_l0_stream<<<dim3(6144), 64, 0, stream>>>(pred, targ, p, slots);
    // L1-4: 2064 single-wave blocks
    ssim_lvls_stream<<<dim3(2064), 64, 0, stream>>>(p, slots);

    finalize_kernel<<<1, 256, 0, stream>>>(slots, out);
}

// Round 12
// 271.628 us; speedup vs baseline: 5.0017x; 1.0051x over previous
//
#include <hip/hip_runtime.h>

// MS-SSIM loss, 5 levels.
// R22: WG-slot discriminator + step-decoupling. Post-mortem R21: block
//   supply (24/CU) did NOT lift occupancy (25->28.7%, cap ~9 waves/CU
//   though LDS allows 14) -> suspect per-CU WORKGROUP-SLOT limit for
//   1-wave WGs. Also block lifetime ~55us for ~4.6K VALU instr = waves
//   95% stalled; two structural stalls: (a) vconv reads the slot
//   written THIS step (ds_write->ds_read lgkmcnt drain on critical
//   path every row); (b) prefetch distance ~1 vconv (~200cy) < L3
//   latency (~450cy). Fixes:
//   (1) 2-wave WGs (128thr), per-wave ring halves ring[2][11][64]
//       (22.5KB -> 7 blocks = 14 waves/CU, same LDS ceiling, half the
//       WG slots). Still barrier-free.
//   (2) newest-slot register bypass: read 10 OLD slots (issued first,
//       covered by H-conv VALU), acc += hnew*G[10] from regs, ds_write
//       hnew AFTER -- no same-step write->read. Reads grouped 5+5
//       with folds between to bound liveness (~90 VGPR peak).
//   (3) reload window buffer right after consumption (next use = one
//       full step later ~400cy); skip dead trailing loads.
//   Discriminator: occ ~40% => WG slots were the cap. Tripwires:
//   WRITE ~38MB, VGPR <= ~100.
// Carried: LDS ring (r20: killed scratch, WRITE 142->41MB); 32-row
// bands (r21); launch_bounds cap = 256/minwaves (r16-r18); channel-
// packed (x,y,xx+yy,xy); pool phase w/ shfl tree; padded pyramid +
// edge-zeroed pads; spread atomics; lane=own-column H.

#define NIMG 48
#define NSLOT 256
#define SSTRIDE 16             // 64 B between slots -> 1 cache line each

// padded pyramid geometry (8 zero cols each side)
#define RS1 272
#define RS2 144
#define RS3 80
#define RS4 48
#define IS0 (512L*512)
#define IS1 (256L*272)
#define IS2 (128L*144)
#define IS3 (64L*80)
#define IS4 (32L*48)

typedef float v4f __attribute__((ext_vector_type(4)));
typedef float uf4 __attribute__((ext_vector_type(4), aligned(4)));

struct Pyr { float *x1, *y1, *x2, *y2, *x3, *y3, *x4, *y4; };

#define GDEF const float G[11] = { \
    0.00102839f, 0.00759877f, 0.03600077f, 0.10936069f, 0.21300539f, \
    0.26601173f, 0.21300539f, 0.10936069f, 0.03600077f, 0.00759877f, \
    0.00102839f };

#define WRAP11(v) (((v) + 1 == 11) ? 0 : (v) + 1)

__device__ __forceinline__ void load12(const float* rp, int cb, float* w)
{
#pragma unroll
    for (int v = 0; v < 3; ++v) {
        const uf4 a = *reinterpret_cast<const uf4*>(rp + cb + 4 * v);
        w[4*v+0] = a.x; w[4*v+1] = a.y; w[4*v+2] = a.z; w[4*v+3] = a.w;
    }
}

__device__ __forceinline__ void load12g(const float* rp, int cb, int W, float* w)
{
#pragma unroll
    for (int e = 0; e < 12; ++e) {
        const int col = cb + e;
        w[e] = ((unsigned)col < (unsigned)W) ? rp[col] : 0.0f;
    }
}

// L0 window load (row l, cols [cb, cb+12)) with edge/row guards
__device__ __forceinline__ void l0_win(const float* xi, const float* yi,
                                       int l, int cb, bool edge,
                                       float* xw, float* yw)
{
    if ((unsigned)l < 512u) {
        const float* xr = xi + (long)l * 512;
        const float* yr = yi + (long)l * 512;
        if (!edge) { load12(xr, cb, xw); load12(yr, cb, yw); }
        else       { load12g(xr, cb, 512, xw); load12g(yr, cb, 512, yw); }
    } else {
#pragma unroll
        for (int e = 0; e < 12; ++e) { xw[e] = 0.f; yw[e] = 0.f; }
    }
}

// pyramid-level window load (col pads cover [-8, W+8))
__device__ __forceinline__ void lv_win(const float* xi, const float* yi,
                                       int l, int cb, int H, int rs,
                                       bool laneOK, float* xw, float* yw)
{
    if (((unsigned)l < (unsigned)H) && laneOK) {
        load12(xi + (long)l * rs, cb, xw);
        load12(yi + (long)l * rs, cb, yw);
    } else {
#pragma unroll
        for (int e = 0; e < 12; ++e) { xw[e] = 0.f; yw[e] = 0.f; }
    }
}

// H-conv at this lane's col: v4f (x, y, xx+yy, xy)
__device__ __forceinline__ v4f h_of_row(const float* xw, const float* yw)
{
    GDEF
    v4f s = {0.f, 0.f, 0.f, 0.f};
#pragma unroll
    for (int k = 0; k < 11; ++k) {
        const float a = xw[k], b = yw[k];
        v4f w; w.x = a; w.y = b; w.z = a*a + b*b; w.w = a*b;
        s += w * G[k];                     // 2x v_pk_fma_f32
    }
    return s;
}

__device__ __forceinline__ float ssim_px(const v4f acc)
{
    const float C1 = 4.0e-4f;
    const float C2 = 3.6e-3f;
    const float mu1 = acc.x, mu2 = acc.y;
    const float mu1s = mu1*mu1, mu2s = mu2*mu2, m12 = mu1*mu2;
    const float ssum = acc.z - mu1s - mu2s;        // sig1+sig2
    const float s12  = acc.w - m12;
    const float num = (2.f * m12 + C1) * (2.f * s12 + C2);
    const float den = (mu1s + mu2s + C1) * (ssum + C2);
    return num * __builtin_amdgcn_rcpf(den + 1e-8f);
}

// One output row: read 10 OLD ring slots (5+5, folds between; latency
// covered by h compute), combine with hnew in regs, THEN publish hnew.
__device__ __forceinline__ float step_row(v4f (*ring)[64], int vb, int wslot,
                                          int lane, const float* xw,
                                          const float* yw)
{
    GDEF
    int sl = vb;
    const v4f q0 = ring[sl][lane]; sl = WRAP11(sl);
    const v4f q1 = ring[sl][lane]; sl = WRAP11(sl);
    const v4f q2 = ring[sl][lane]; sl = WRAP11(sl);
    const v4f q3 = ring[sl][lane]; sl = WRAP11(sl);
    const v4f q4 = ring[sl][lane]; sl = WRAP11(sl);
    const v4f hnew = h_of_row(xw, yw);      // VALU covers the ds_reads
    v4f acc = q0 * G[0];
    acc += q1 * G[1]; acc += q2 * G[2]; acc += q3 * G[3]; acc += q4 * G[4];
    const v4f q5 = ring[sl][lane]; sl = WRAP11(sl);
    const v4f q6 = ring[sl][lane]; sl = WRAP11(sl);
    const v4f q7 = ring[sl][lane]; sl = WRAP11(sl);
    const v4f q8 = ring[sl][lane]; sl = WRAP11(sl);
    const v4f q9 = ring[sl][lane];
    acc += q5 * G[5]; acc += q6 * G[6]; acc += q7 * G[7]; acc += q8 * G[8];
    acc += q9 * G[9]; acc += hnew * G[10];
    ring[wslot][lane] = hnew;               // no reader this step
    return ssim_px(acc);
}

// ---- L0: pool (head) + streaming SSIM. 3072 blocks x 128 thr ----
// wave wid: band = wid&15 (32 rows), strip = (wid>>4)&7, z = wid>>7.
__global__ __launch_bounds__(128, 2) void ssim_l0_stream(
    const float* __restrict__ x, const float* __restrict__ y,
    Pyr p, float* __restrict__ slots)
{
    __shared__ __align__(16) v4f ring[2][11][64];  // 22528 B -> 7 blocks/CU

    const int t     = threadIdx.x;
    const int lane  = t & 63;
    const int wid   = blockIdx.x * 2 + (t >> 6);
    const int R0    = (wid & 15) * 32;
    const int strip = (wid >> 4) & 7;
    const int C0    = strip * 64;
    const int z     = wid >> 7;
    const float* xi = x + (long)z * IS0;
    const float* yi = y + (long)z * IS0;
    const bool edge = (strip == 0) | (strip == 7);
    v4f (*myring)[64] = ring[t >> 6];

    float* q1x = p.x1 + (long)z * IS1;  float* q1y = p.y1 + (long)z * IS1;
    float* q2x = p.x2 + (long)z * IS2;  float* q2y = p.y2 + (long)z * IS2;
    float* q3x = p.x3 + (long)z * IS3;  float* q3y = p.y3 + (long)z * IS3;
    float* q4x = p.x4 + (long)z * IS4;  float* q4y = p.y4 + (long)z * IS4;

    // ---- pool phase: lane owns an 8-col x 4-row patch of the 64x32 tile ----
    {
        const int r8 = lane >> 3, c8 = lane & 7;
        const int pr0 = R0 + 4 * r8, pc0 = C0 + 8 * c8;
        float v2x0, v2x1, v2y0, v2y1;
        {
            float sx0 = 0.f, sx1 = 0.f, sy0 = 0.f, sy1 = 0.f;
#pragma unroll
            for (int rp = 0; rp < 2; ++rp) {       // row pairs (0,1), (2,3)
                const int ir = pr0 + 2 * rp;
                const float* xr = xi + (long)ir * 512 + pc0;
                const float* yr = yi + (long)ir * 512 + pc0;
                const float4 a0 = *reinterpret_cast<const float4*>(xr);
                const float4 a1 = *reinterpret_cast<const float4*>(xr + 4);
                const float4 a2 = *reinterpret_cast<const float4*>(xr + 512);
                const float4 a3 = *reinterpret_cast<const float4*>(xr + 516);
                const float4 b0 = *reinterpret_cast<const float4*>(yr);
                const float4 b1 = *reinterpret_cast<const float4*>(yr + 4);
                const float4 b2 = *reinterpret_cast<const float4*>(yr + 512);
                const float4 b3 = *reinterpret_cast<const float4*>(yr + 516);
                const float qx0 = 0.25f*(a0.x+a0.y+a2.x+a2.y);
                const float qx1 = 0.25f*(a0.z+a0.w+a2.z+a2.w);
                const float qx2 = 0.25f*(a1.x+a1.y+a3.x+a3.y);
                const float qx3 = 0.25f*(a1.z+a1.w+a3.z+a3.w);
                const float qy0 = 0.25f*(b0.x+b0.y+b2.x+b2.y);
                const float qy1 = 0.25f*(b0.z+b0.w+b2.z+b2.w);
                const float qy2 = 0.25f*(b1.x+b1.y+b3.x+b3.y);
                const float qy3 = 0.25f*(b1.z+b1.w+b3.z+b3.w);
                float4 ox; ox.x=qx0; ox.y=qx1; ox.z=qx2; ox.w=qx3;
                float4 oy; oy.x=qy0; oy.y=qy1; oy.z=qy2; oy.w=qy3;
                const int r1 = (R0 >> 1) + 2*r8 + rp;
                *reinterpret_cast<float4*>(q1x + (long)r1*RS1 + (pc0>>1)) = ox;
                *reinterpret_cast<float4*>(q1y + (long)r1*RS1 + (pc0>>1)) = oy;
                sx0 += qx0+qx1; sx1 += qx2+qx3;
                sy0 += qy0+qy1; sy1 += qy2+qy3;
            }
            v2x0 = 0.25f*sx0; v2x1 = 0.25f*sx1;
            v2y0 = 0.25f*sy0; v2y1 = 0.25f*sy1;
            *reinterpret_cast<float2*>(q2x + (long)((R0>>2)+r8)*RS2 + (pc0>>2))
                = make_float2(v2x0, v2x1);
            *reinterpret_cast<float2*>(q2y + (long)((R0>>2)+r8)*RS2 + (pc0>>2))
                = make_float2(v2y0, v2y1);
        }
        const float s3x = v2x0 + v2x1, s3y = v2y0 + v2y1;
        const float v3x = 0.25f*(s3x + __shfl_down(s3x, 8, 64));
        const float v3y = 0.25f*(s3y + __shfl_down(s3y, 8, 64));
        if (!(r8 & 1)) {
            q3x[(long)((R0>>3)+(r8>>1))*RS3 + (C0>>3)+c8] = v3x;
            q3y[(long)((R0>>3)+(r8>>1))*RS3 + (C0>>3)+c8] = v3y;
        }
        const float v4x = 0.25f*(v3x + __shfl_down(v3x,1,64)
                               + __shfl_down(v3x,16,64) + __shfl_down(v3x,17,64));
        const float v4y = 0.25f*(v3y + __shfl_down(v3y,1,64)
                               + __shfl_down(v3y,16,64) + __shfl_down(v3y,17,64));
        if (!(r8 & 3) && !(c8 & 1)) {
            q4x[(long)((R0>>4)+(r8>>2))*RS4 + (C0>>4)+(c8>>1)] = v4x;
            q4y[(long)((R0>>4)+(r8>>2))*RS4 + (C0>>4)+(c8>>1)] = v4y;
        }
        if (edge) {
            const bool left = (strip == 0);
            const int p1c = left ? (c8 - 8) : (256 + c8);
            const int p2c = left ? (c8 - 8) : (128 + c8);
            const int p3c = left ? (c8 - 8) : (64 + c8);
            const int p4c = left ? (c8 - 8) : (32 + c8);
#pragma unroll
            for (int i = 0; i < 2; ++i) {          // x1: 16 pad rows
                const int rr = (R0>>1) + 8*i + r8;
                q1x[(long)rr*RS1 + p1c] = 0.f; q1y[(long)rr*RS1 + p1c] = 0.f;
            }
            { const int rr = (R0>>2) + r8;         // x2: 8 pad rows
              q2x[(long)rr*RS2 + p2c] = 0.f; q2y[(long)rr*RS2 + p2c] = 0.f; }
            if (r8 < 4) {                          // x3: 4 pad rows
                const int rr = (R0>>3) + r8;
                q3x[(long)rr*RS3 + p3c] = 0.f; q3y[(long)rr*RS3 + p3c] = 0.f;
            }
            if (r8 < 2) {                          // x4: 2 pad rows
                const int rr = (R0>>4) + r8;
                q4x[(long)rr*RS4 + p4c] = 0.f; q4y[(long)rr*RS4 + p4c] = 0.f;
            }
        }
    }
    __builtin_amdgcn_sched_barrier(0);   // keep stream loads out of pool phase

    // ---- streaming SSIM: LDS ring + bypass, post-consume reload ----
    const int cb = C0 + lane - 5;
    float local = 0.f;

#pragma unroll 1
    for (int s = 0; s < 10; ++s) {       // rows R0-5 .. R0+4 -> slots 0..9
        float xw[12], yw[12];
        l0_win(xi, yi, R0 - 5 + s, cb, edge, xw, yw);
        myring[s][lane] = h_of_row(xw, yw);
    }

    float xwa[12], ywa[12], xwb[12], ywb[12];
    l0_win(xi, yi, R0 + 5, cb, edge, xwa, ywa);
    l0_win(xi, yi, R0 + 6, cb, edge, xwb, ywb);
    int wslot = 10, vb = 0, lload = R0 + 7;
#pragma unroll 1
    for (int pp = 0; pp < 16; ++pp) {
        local += step_row(myring, vb, wslot, lane, xwa, ywa);
        wslot = WRAP11(wslot); vb = WRAP11(vb);
        if (pp < 15) { l0_win(xi, yi, lload, cb, edge, xwa, ywa); ++lload; }
        local += step_row(myring, vb, wslot, lane, xwb, ywb);
        wslot = WRAP11(wslot); vb = WRAP11(vb);
        if (pp < 15) { l0_win(xi, yi, lload, cb, edge, xwb, ywb); ++lload; }
    }

#pragma unroll
    for (int off = 32; off > 0; off >>= 1) local += __shfl_down(local, off, 64);
    if (lane == 0) atomicAdd(slots + (wid & (NSLOT - 1)) * SSTRIDE, local);
}

// ---- levels 1-4, streaming, 32-row bands. 1032 blocks x 128 thr ----
// wid: L1 0..1535, L2 ..1919, L3 ..2015, L4 ..2063.
__global__ __launch_bounds__(128, 2) void ssim_lvls_stream(
    Pyr p, float* __restrict__ slots)
{
    __shared__ __align__(16) v4f ring[2][11][64];

    const int t    = threadIdx.x;
    const int lane = t & 63;
    const int wid  = blockIdx.x * 2 + (t >> 6);
    v4f (*myring)[64] = ring[t >> 6];

    const float* xi; const float* yi;
    int rs, H, W, C0, R0, lvl;
    if (wid < 1536) {
        lvl = 1; const int r = wid & 31, z = wid >> 5;
        xi = p.x1 + (long)z * IS1; yi = p.y1 + (long)z * IS1;
        rs = RS1; H = W = 256; C0 = (r & 3) * 64; R0 = (r >> 2) * 32;
    } else if (wid < 1920) {
        lvl = 2; const int w2 = wid - 1536; const int r = w2 & 7, z = w2 >> 3;
        xi = p.x2 + (long)z * IS2; yi = p.y2 + (long)z * IS2;
        rs = RS2; H = W = 128; C0 = (r & 1) * 64; R0 = (r >> 1) * 32;
    } else if (wid < 2016) {
        lvl = 3; const int w2 = wid - 1920; const int by = w2 & 1, z = w2 >> 1;
        xi = p.x3 + (long)z * IS3; yi = p.y3 + (long)z * IS3;
        rs = RS3; H = W = 64; C0 = 0; R0 = by * 32;
    } else {
        lvl = 4; const int z = wid - 2016;
        xi = p.x4 + (long)z * IS4; yi = p.y4 + (long)z * IS4;
        rs = RS4; H = W = 32; C0 = 0; R0 = 0;
    }
    const int cb = C0 + lane - 5;
    const bool laneOK = (C0 + lane) < W;
    float local = 0.f;

#pragma unroll 1
    for (int s = 0; s < 10; ++s) {
        float xw[12], yw[12];
        lv_win(xi, yi, R0 - 5 + s, cb, H, rs, laneOK, xw, yw);
        myring[s][lane] = h_of_row(xw, yw);
    }

    float xwa[12], ywa[12], xwb[12], ywb[12];
    lv_win(xi, yi, R0 + 5, cb, H, rs, laneOK, xwa, ywa);
    lv_win(xi, yi, R0 + 6, cb, H, rs, laneOK, xwb, ywb);
    int wslot = 10, vb = 0, lload = R0 + 7;
#pragma unroll 1
    for (int pp = 0; pp < 16; ++pp) {
        { const float r = step_row(myring, vb, wslot, lane, xwa, ywa);
          if (laneOK) local += r; }
        wslot = WRAP11(wslot); vb = WRAP11(vb);
        if (pp < 15) { lv_win(xi, yi, lload, cb, H, rs, laneOK, xwa, ywa); ++lload; }
        { const float r = step_row(myring, vb, wslot, lane, xwb, ywb);
          if (laneOK) local += r; }
        wslot = WRAP11(wslot); vb = WRAP11(vb);
        if (pp < 15) { lv_win(xi, yi, lload, cb, H, rs, laneOK, xwb, ywb); ++lload; }
    }

#pragma unroll
    for (int off = 32; off > 0; off >>= 1) local += __shfl_down(local, off, 64);
    if (lane == 0)
        atomicAdd(slots + ((long)lvl * NSLOT + (wid & (NSLOT - 1))) * SSTRIDE,
                  local);
}

__global__ void finalize_kernel(const float* __restrict__ slots,
                                float* __restrict__ out)
{
    const int t = threadIdx.x;
    const float w[5] = {0.0448f, 0.2856f, 0.3001f, 0.2363f, 0.1333f};
    const float wsum = w[0] + w[1] + w[2] + w[3] + w[4];
    float acc = 0.f;
#pragma unroll
    for (int lvl = 0; lvl < 5; ++lvl) {
        const int d = 512 >> lvl;
        const float cnt = (float)NIMG * (float)d * (float)d;
        acc += (w[lvl] / wsum) / cnt * slots[(lvl * NSLOT + t) * SSTRIDE];
    }
#pragma unroll
    for (int off = 32; off > 0; off >>= 1) acc += __shfl_down(acc, off, 64);
    __shared__ float pp[4];
    if ((t & 63) == 0) pp[t >> 6] = acc;
    __syncthreads();
    if (t == 0) out[0] = 1.0f - (pp[0] + pp[1] + pp[2] + pp[3]);
}

extern "C" void kernel_launch(void* const* d_in, const int* in_sizes, int n_in,
                              void* d_out, int out_size, void* d_ws, size_t ws_size,
                              hipStream_t stream)
{
    const float* pred = (const float*)d_in[0];
    const float* targ = (const float*)d_in[1];
    float* out = (float*)d_out;
    float* ws  = (float*)d_ws;

    float* slots = ws;                           // 5 * 256 * 16 floats (80 KB)
    float* zpad  = slots + 5 * NSLOT * SSTRIDE;  // 640 floats (layout compat)

    Pyr p;
    {
        float* b = zpad + 640;
        p.x1 = b + 8;                 b += NIMG * IS1;
        p.y1 = b + 8;                 b += NIMG * IS1;
        p.x2 = b + 8;                 b += NIMG * IS2;
        p.y2 = b + 8;                 b += NIMG * IS2;
        p.x3 = b + 8;                 b += NIMG * IS3;
        p.y3 = b + 8;                 b += NIMG * IS3;
        p.x4 = b + 8;                 b += NIMG * IS4;
        p.y4 = b + 8;
    }

    hipMemsetAsync(ws, 0, (size_t)(5 * NSLOT * SSTRIDE + 640) * sizeof(float),
                   stream);

    // L0 + fused pyramid: 6144 waves in 3072 two-wave blocks
    ssim_l0_stream<<<dim3(3072), 128, 0, stream>>>(pred, targ, p, slots);
    // L1-4: 2064 waves in 1032 two-wave blocks
    ssim_lvls_stream<<<dim3(1032), 128, 0, stream>>>(p, slots);

    finalize_kernel<<<1, 256, 0, stream>>>(slots, out);
}